// Round 2
// baseline (7696.281 us; speedup 1.0000x reference)
//
#include <hip/hip_runtime.h>
#include <hip/hip_bf16.h>
#include <math.h>

typedef __hip_bfloat16 bf16;
typedef unsigned int u32;

#define B_      128
#define T_      100
#define ENC_IN_ 38
#define DM_     512
#define H_      8
#define HD_     64
#define L_      3
#define NTOK    (B_*T_)      /* 12800 */
#define K_CB    50           /* codebook size */

#define OUT_N     486400      /* B*T*C_OUT */
#define SER_N     30720000    /* L*B*H*T*T */
#define SER_PER_L 10240000    /* B*H*T*T */
#define SCALAR_BASE (OUT_N + SER_N)   /* 31206400 */

#define PROJ_KS 16            /* split-K factor for the final projection GEMM */

// Dual-dtype input load: inputs are either all-f32 or all-bf16. Element offset
// applied AFTER dtype resolution (a bf16*-typed base + offset would be wrong
// in the f32 world).
__device__ __forceinline__ float ldin(const void* p, size_t i, int f32) {
    if (f32) return ((const float*)p)[i];
    return __bfloat162float(((const bf16*)p)[i]);
}
__device__ __forceinline__ void stout(void* p, size_t i, float v, int f32) {
    if (f32) ((float*)p)[i] = v;
    else     ((bf16*)p)[i] = __float2bfloat16(v);
}

// ---------------------------------------------------------------------------
// init: zero scalar accumulators acc[0..6]; detect input dtype from ln1g
// (all-ones): f32 -> first u32 = 0x3F800000, bf16 -> 0x3F803F80.
// ---------------------------------------------------------------------------
__global__ void init_kernel(const void* ln1g, float* acc) {
    if (threadIdx.x < 7) acc[threadIdx.x] = 0.f;
    if (threadIdx.x == 7) {
        u32 w0 = *(const u32*)ln1g;
        ((int*)acc)[7] = (w0 == 0x3F800000u) ? 1 : 0;
    }
}

// ---------------------------------------------------------------------------
// Embedding: circular conv1d(k=3) + sinusoidal positions. Block per token.
// ---------------------------------------------------------------------------
__launch_bounds__(512)
__global__ void embed_kernel(const void* __restrict__ x, const void* __restrict__ w,
                             const int* __restrict__ flg, float* __restrict__ h) {
    __shared__ float xs[3*ENC_IN_];
    const int f32 = flg[0];
    const int blk = blockIdx.x;
    const int b = blk / T_, t = blk - b*T_;
    const int tid = threadIdx.x;
    if (tid < 3*ENC_IN_) {
        int wv = tid / ENC_IN_, c = tid - wv*ENC_IN_;
        int rr = t - 1 + wv; rr = (rr + T_) % T_;
        xs[tid] = ldin(x, ((size_t)b*T_ + rr)*ENC_IN_ + c, f32);
    }
    __syncthreads();
    int i2 = tid & ~1;
    float freq = expf(-(float)i2 * (9.210340371976184f / 512.f));
    float ang = (float)t * freq;
    float s = (tid & 1) ? cosf(ang) : sinf(ang);
    for (int j = 0; j < 3*ENC_IN_; ++j)
        s = fmaf(xs[j], ldin(w, (size_t)j*DM_ + tid, f32), s);
    h[(size_t)blk*DM_ + tid] = s;
}

// ---------------------------------------------------------------------------
// Generic small GEMM: C = act(A @ op(B) + bias). 64x64 tile, 256 threads,
// 4x4 microtile. Used for N < 512 (decoder-side small GEMMs) where a 128-wide
// tile would collapse the grid.
// ---------------------------------------------------------------------------
template<int ACT, int TRANSB>
__launch_bounds__(256)
__global__ void gemm_kernel(const float* __restrict__ A, const void* __restrict__ Bw,
                            size_t bwoff, const void* __restrict__ bias, size_t biasoff,
                            const int* __restrict__ flg,
                            float* __restrict__ C, int M, int N, int K) {
    __shared__ float As[16][68];
    __shared__ float Bs[16][68];
    const int f32 = flg[0];
    const int tid = threadIdx.x;
    const int tx = tid & 15, ty = tid >> 4;
    const int m0 = blockIdx.y * 64, n0 = blockIdx.x * 64;
    float acc[4][4] = {};
    for (int k0 = 0; k0 < K; k0 += 16) {
        for (int i = tid; i < 1024; i += 256) {
            int r = i >> 4, kk = i & 15;
            int gm = m0 + r, gk = k0 + kk;
            As[kk][r] = (gm < M && gk < K) ? A[(size_t)gm*K + gk] : 0.f;
        }
        for (int i = tid; i < 1024; i += 256) {
            int kk, c;
            if (TRANSB) { c = i >> 4; kk = i & 15; }
            else        { kk = i >> 6; c = i & 63; }
            int gk = k0 + kk, gn = n0 + c;
            float vv = 0.f;
            if (gk < K && gn < N)
                vv = TRANSB ? ldin(Bw, bwoff + (size_t)gn*K + gk, f32)
                            : ldin(Bw, bwoff + (size_t)gk*N + gn, f32);
            Bs[kk][c] = vv;
        }
        __syncthreads();
#pragma unroll
        for (int kk = 0; kk < 16; ++kk) {
            float4 av = *(const float4*)&As[kk][ty*4];
            float4 bv = *(const float4*)&Bs[kk][tx*4];
            float a[4] = {av.x, av.y, av.z, av.w};
            float b[4] = {bv.x, bv.y, bv.z, bv.w};
#pragma unroll
            for (int ii = 0; ii < 4; ++ii)
#pragma unroll
                for (int jj = 0; jj < 4; ++jj)
                    acc[ii][jj] = fmaf(a[ii], b[jj], acc[ii][jj]);
        }
        __syncthreads();
    }
#pragma unroll
    for (int ii = 0; ii < 4; ++ii) {
        int gm = m0 + ty*4 + ii;
        if (gm >= M) continue;
#pragma unroll
        for (int jj = 0; jj < 4; ++jj) {
            int gn = n0 + tx*4 + jj;
            if (gn >= N) continue;
            float vv = acc[ii][jj] + (bias ? ldin(bias, biasoff + gn, f32) : 0.f);
            if (ACT == 1) vv = 0.5f * vv * (1.f + erff(vv * 0.7071067811865475f));
            if (ACT == 2) vv = fmaxf(vv, 0.f);
            C[(size_t)gm*N + gn] = vv;
        }
    }
}

// ---------------------------------------------------------------------------
// Big-tile GEMM: 128x128 tile, 256 threads, 8x8 microtile. The 4x4 microtile
// kernel needs 256 B/cy of LDS reads to feed 128 FMA/cy (LDS peak is 128 B/cy)
// -> structurally LDS-bound at <=50% VALU (measured VALUBusy 32%). 8x8 gives
// 64 FMA per 64 B LDS -> VALU-issue-bound. Requires K % 16 == 0.
// SPLITK: accumulate over a K-chunk and atomicAdd into pre-biased C.
// ---------------------------------------------------------------------------
template<int ACT, int TRANSB, int SPLITK>
__launch_bounds__(256)
__global__ void gemm128_kernel(const float* __restrict__ A, const void* __restrict__ Bw,
                               size_t bwoff, const void* __restrict__ bias, size_t biasoff,
                               const int* __restrict__ flg, float* __restrict__ C,
                               int M, int N, int K, int kchunk) {
    __shared__ float As[16][132];
    __shared__ float Bs[16][132];
    const int f32 = flg[0];
    const int tid = threadIdx.x;
    const int tx = tid & 15, ty = tid >> 4;
    const int m0 = blockIdx.y * 128, n0 = blockIdx.x * 128;
    int kbeg = 0, kend = K;
    if (SPLITK) { kbeg = blockIdx.z * kchunk; kend = kbeg + kchunk; }
    float acc[8][8] = {};
    for (int k0 = kbeg; k0 < kend; k0 += 16) {
        // stage A tile (128 rows x 16 k), transposed into As[kk][row]
        for (int i = tid; i < 2048; i += 256) {
            int r = i >> 4, kk = i & 15;
            int gm = m0 + r;
            As[kk][r] = (gm < M) ? A[(size_t)gm*K + (k0 + kk)] : 0.f;
        }
        // stage B tile (16 k x 128 n)
        for (int i = tid; i < 2048; i += 256) {
            int kk, c;
            if (TRANSB) { c = i >> 4; kk = i & 15; }
            else        { kk = i >> 7; c = i & 127; }
            int gn = n0 + c;
            float vv = 0.f;
            if (gn < N)
                vv = TRANSB ? ldin(Bw, bwoff + (size_t)gn*K + (k0 + kk), f32)
                            : ldin(Bw, bwoff + (size_t)(k0 + kk)*N + gn, f32);
            Bs[kk][c] = vv;
        }
        __syncthreads();
#pragma unroll
        for (int kk = 0; kk < 16; ++kk) {
            float4 a0 = *(const float4*)&As[kk][ty*8];
            float4 a1 = *(const float4*)&As[kk][ty*8 + 4];
            float4 b0 = *(const float4*)&Bs[kk][tx*8];
            float4 b1 = *(const float4*)&Bs[kk][tx*8 + 4];
            float a[8] = {a0.x,a0.y,a0.z,a0.w,a1.x,a1.y,a1.z,a1.w};
            float b[8] = {b0.x,b0.y,b0.z,b0.w,b1.x,b1.y,b1.z,b1.w};
#pragma unroll
            for (int ii = 0; ii < 8; ++ii)
#pragma unroll
                for (int jj = 0; jj < 8; ++jj)
                    acc[ii][jj] = fmaf(a[ii], b[jj], acc[ii][jj]);
        }
        __syncthreads();
    }
    if (SPLITK) {
#pragma unroll
        for (int ii = 0; ii < 8; ++ii) {
            int gm = m0 + ty*8 + ii;
            if (gm >= M) continue;
#pragma unroll
            for (int jj = 0; jj < 8; ++jj) {
                int gn = n0 + tx*8 + jj;
                if (gn >= N) continue;
                atomicAdd(&C[(size_t)gm*N + gn], acc[ii][jj]);
            }
        }
    } else {
#pragma unroll
        for (int ii = 0; ii < 8; ++ii) {
            int gm = m0 + ty*8 + ii;
            if (gm >= M) continue;
#pragma unroll
            for (int jj = 0; jj < 8; ++jj) {
                int gn = n0 + tx*8 + jj;
                if (gn >= N) continue;
                float vv = acc[ii][jj] + (bias ? ldin(bias, biasoff + gn, f32) : 0.f);
                if (ACT == 1) vv = 0.5f * vv * (1.f + erff(vv * 0.7071067811865475f));
                if (ACT == 2) vv = fmaxf(vv, 0.f);
                C[(size_t)gm*N + gn] = vv;
            }
        }
    }
}

// ---------------------------------------------------------------------------
// Bias prefill for the split-K projection GEMM output.
// ---------------------------------------------------------------------------
__launch_bounds__(256)
__global__ void proj_init_kernel(const void* __restrict__ bias,
                                 const int* __restrict__ flg,
                                 float* __restrict__ C) {
    int i = blockIdx.x*256 + threadIdx.x;
    if (i < OUT_N) C[i] = ldin(bias, (size_t)(i % 3800), flg[0]);
}

// ---------------------------------------------------------------------------
// Independent series kernel: one block per (b, h, t) query row. 128 threads;
// thread s (<100) computes logit = 0.125 * q_t . k_s from the q/k projection
// buffers in GLOBAL memory, block-LDS softmax over s, direct dual-dtype store
// at series[l][b][h][t][s]. No shuffles, no aliasing, no shared state.
// ---------------------------------------------------------------------------
__launch_bounds__(128)
__global__ void series_kernel(const float* __restrict__ Q, const float* __restrict__ Kg,
                              void* __restrict__ outb, size_t soff,
                              const int* __restrict__ flg) {
    __shared__ float qs[64];
    __shared__ float red[128];
    const int t = blockIdx.x, hh = blockIdx.y, b = blockIdx.z;
    const int tid = threadIdx.x;
    const size_t base = (size_t)b*T_*DM_ + (size_t)hh*HD_;
    if (tid < 64) qs[tid] = Q[base + (size_t)t*DM_ + tid];
    __syncthreads();
    float lg = -1e30f;
    if (tid < T_) {
        const float* kr = Kg + base + (size_t)tid*DM_;
        float dot = 0.f;
#pragma unroll 8
        for (int d = 0; d < 64; ++d) dot = fmaf(qs[d], kr[d], dot);
        lg = dot * 0.125f;
    }
    red[tid] = lg;
    __syncthreads();
    for (int st = 64; st > 0; st >>= 1) { if (tid < st) red[tid] = fmaxf(red[tid], red[tid+st]); __syncthreads(); }
    const float mx = red[0];
    __syncthreads();
    float e = (tid < T_) ? expf(lg - mx) : 0.f;
    red[tid] = e;
    __syncthreads();
    for (int st = 64; st > 0; st >>= 1) { if (tid < st) red[tid] += red[tid+st]; __syncthreads(); }
    const float inv = 1.f / red[0];
    if (tid < T_)
        stout(outb, soff + ((size_t)(b*H_ + hh)*T_ + t)*T_ + tid, e * inv, flg[0]);
}

// ---------------------------------------------------------------------------
// Fused attention context for one (b, head): C = softmax(0.125 Q K^T) V.
// (series now written by series_kernel; this kernel only produces context.)
// ---------------------------------------------------------------------------
__launch_bounds__(256)
__global__ void attn_kernel(const float* Q, const float* __restrict__ Kg,
                            const float* __restrict__ Vg, float* Cg) {
    __shared__ float Ks[T_*65];
    __shared__ float Vs[T_*65];
    __shared__ float Qrow[4][64];
    __shared__ float Prow[4][104];
    const int tid = threadIdx.x;
    const int lane = tid & 63, w = tid >> 6;
    const int hh = blockIdx.x, b = blockIdx.y;
    const size_t base = (size_t)b*T_*DM_ + (size_t)hh*HD_;
    for (int i = tid; i < T_*HD_; i += 256) {
        int r = i >> 6, d = i & 63;
        size_t g = base + (size_t)r*DM_ + d;
        Ks[r*65+d] = Kg[g];
        Vs[r*65+d] = Vg[g];
    }
    __syncthreads();
    for (int i = 0; i < 25; ++i) {
        const int t = i*4 + w;
        Qrow[w][lane] = Q[base + (size_t)t*DM_ + lane];
        __syncthreads();
        const int s2 = 64 + lane;
        float acc1 = 0.f, acc2 = 0.f;
#pragma unroll 16
        for (int d = 0; d < 64; ++d) {
            float qd = Qrow[w][d];
            acc1 = fmaf(qd, Ks[lane*65 + d], acc1);
            if (s2 < T_) acc2 = fmaf(qd, Ks[s2*65 + d], acc2);
        }
        acc1 *= 0.125f; acc2 *= 0.125f;
        float mx = (s2 < T_) ? fmaxf(acc1, acc2) : acc1;
        for (int off = 32; off > 0; off >>= 1) mx = fmaxf(mx, __shfl_xor(mx, off));
        float e1 = expf(acc1 - mx);
        float e2 = (s2 < T_) ? expf(acc2 - mx) : 0.f;
        float sum = e1 + e2;
        for (int off = 32; off > 0; off >>= 1) sum += __shfl_xor(sum, off);
        float inv = 1.f / sum;
        Prow[w][lane] = e1 * inv;
        if (s2 < T_) Prow[w][s2] = e2 * inv;
        __syncthreads();
        float o = 0.f;
#pragma unroll 10
        for (int s = 0; s < T_; ++s)
            o = fmaf(Prow[w][s], Vs[s*65 + lane], o);
        Cg[base + (size_t)t*DM_ + lane] = o;
    }
}

// ---------------------------------------------------------------------------
// Residual + LayerNorm over 512 dims; in-place on h; gamma/beta dual-dtype
// with element offsets.
// ---------------------------------------------------------------------------
__launch_bounds__(256)
__global__ void ln_kernel(float* __restrict__ h, const float* __restrict__ res,
                          const void* __restrict__ g, const void* __restrict__ bta,
                          size_t goff, const int* __restrict__ flg) {
    __shared__ float red[256];
    const int f32 = flg[0];
    const int row = blockIdx.x, tid = threadIdx.x;
    float* hp = h + (size_t)row*DM_;
    float x0 = hp[tid], x1 = hp[tid+256];
    if (res) {
        x0 += res[(size_t)row*DM_ + tid];
        x1 += res[(size_t)row*DM_ + tid + 256];
    }
    red[tid] = x0 + x1;
    __syncthreads();
    for (int s = 128; s > 0; s >>= 1) { if (tid < s) red[tid] += red[tid+s]; __syncthreads(); }
    float mean = red[0] * (1.f/512.f);
    __syncthreads();
    float d0 = x0 - mean, d1 = x1 - mean;
    red[tid] = d0*d0 + d1*d1;
    __syncthreads();
    for (int s = 128; s > 0; s >>= 1) { if (tid < s) red[tid] += red[tid+s]; __syncthreads(); }
    float rs = 1.f / sqrtf(red[0]*(1.f/512.f) + 1e-5f);
    hp[tid]     = d0*rs*ldin(g, goff+tid, f32)     + ldin(bta, goff+tid, f32);
    hp[tid+256] = d1*rs*ldin(g, goff+tid+256, f32) + ldin(bta, goff+tid+256, f32);
}

// ---------------------------------------------------------------------------
__global__ void concat_kernel(const float* __restrict__ h1, const float* __restrict__ ma,
                              float* __restrict__ hb, int n) {
    int i = blockIdx.x*blockDim.x + threadIdx.x;
    if (i >= n) return;
    int row = i / 192, j = i - row*192;
    hb[i] = (j < 128) ? h1[(size_t)row*128 + j] : ma[(size_t)row*64 + (j-128)];
}

// ---------------------------------------------------------------------------
// OT concept head, one block (64 threads) per token.
// ---------------------------------------------------------------------------
__launch_bounds__(64)
__global__ void ot_kernel(const float* __restrict__ pm, const void* __restrict__ theta,
                          const int* __restrict__ flg,
                          float* __restrict__ embv, float* __restrict__ acc) {
    __shared__ float th[K_CB*64];
    __shared__ float pmv[64];
    __shared__ float red[64];
    __shared__ float pvec[64];
    const int f32 = flg[0];
    const int tid = threadIdx.x;
    const int tok = blockIdx.x;
    for (int i = tid; i < K_CB*64; i += 64) th[i] = ldin(theta, i, f32);
    pmv[tid] = pm[(size_t)tok*64 + tid];
    __syncthreads();
    red[tid] = pmv[tid]*pmv[tid];
    __syncthreads();
    for (int s = 32; s > 0; s >>= 1) { if (tid < s) red[tid] += red[tid+s]; __syncthreads(); }
    float pm2 = red[0];
    __syncthreads();
    float cost = 0.f;
    if (tid < K_CB) {
        const float* tr = th + tid*64;
        float dot = 0.f, t2 = 0.f;
        for (int d = 0; d < 64; ++d) { float tv = tr[d]; dot = fmaf(pmv[d], tv, dot); t2 = fmaf(tv, tv, t2); }
        cost = pm2 - 2.f*dot + t2;
    }
    float logit = (tid < K_CB) ? (-cost / 0.1f) : -1e30f;
    red[tid] = logit;
    __syncthreads();
    for (int s = 32; s > 0; s >>= 1) { if (tid < s) red[tid] = fmaxf(red[tid], red[tid+s]); __syncthreads(); }
    float mx = red[0];
    __syncthreads();
    float e = (tid < K_CB) ? expf(logit - mx) : 0.f;
    red[tid] = e;
    __syncthreads();
    for (int s = 32; s > 0; s >>= 1) { if (tid < s) red[tid] += red[tid+s]; __syncthreads(); }
    float p = e / red[0];
    __syncthreads();
    pvec[tid] = p;
    red[tid] = p * cost;
    __syncthreads();
    for (int s = 32; s > 0; s >>= 1) { if (tid < s) red[tid] += red[tid+s]; __syncthreads(); }
    if (tid == 0) atomicAdd(acc + 0, red[0]);
    __syncthreads();
    float eb = 0.f;
    for (int kk = 0; kk < K_CB; ++kk) eb = fmaf(pvec[kk], th[kk*64 + tid], eb);
    embv[(size_t)tok*64 + tid] = eb;
    float dd = eb - pmv[tid];
    red[tid] = dd*dd;
    __syncthreads();
    for (int s = 32; s > 0; s >>= 1) { if (tid < s) red[tid] += red[tid+s]; __syncthreads(); }
    if (tid == 0) atomicAdd(acc + 1, red[0]);
}

// ---------------------------------------------------------------------------
__global__ void klc_kernel(const float* __restrict__ m, const float* __restrict__ lv,
                           float* __restrict__ acc) {
    __shared__ float red[256];
    const int tid = threadIdx.x;
    float s = 0.f;
    for (int i = blockIdx.x*256 + tid; i < NTOK*64; i += gridDim.x*256) {
        float mm = m[i], l = lv[i];
        s += -0.5f * (1.f - mm*mm + l - expf(l));
    }
    red[tid] = s; __syncthreads();
    for (int st = 128; st > 0; st >>= 1) { if (tid < st) red[tid] += red[tid+st]; __syncthreads(); }
    if (tid == 0) atomicAdd(acc + 2, red[0]);
}

__global__ void klz_kernel(const float* __restrict__ dzm, const float* __restrict__ zm,
                           const float* __restrict__ zlv, const float* __restrict__ dzl,
                           float* __restrict__ acc) {
    __shared__ float red[256];
    const int tid = threadIdx.x;
    float s = 0.f;
    for (int i = blockIdx.x*256 + tid; i < NTOK*128; i += gridDim.x*256) {
        float d = dzm[i] - zm[i];
        float zl = zlv[i], dl = dzl[i];
        s += 0.5f * (d*d / expf(zl) + expf(dl - zl) - 1.f - (dl - zl));
    }
    red[tid] = s; __syncthreads();
    for (int st = 128; st > 0; st >>= 1) { if (tid < st) red[tid] += red[tid+st]; __syncthreads(); }
    if (tid == 0) atomicAdd(acc + 3, red[0]);
}

// ---------------------------------------------------------------------------
__global__ void finalize_kernel(const float* __restrict__ outf, const float* __restrict__ acc,
                                void* __restrict__ outb) {
    const int f32 = ((const int*)acc)[7];
    int i = blockIdx.x*blockDim.x + threadIdx.x;
    if (i < OUT_N) stout(outb, i, outf[i], f32);
    if (i == 0) {
        stout(outb, SCALAR_BASE + 0, acc[0] * (1.f/12800.f),   f32);
        stout(outb, SCALAR_BASE + 1, acc[1] * (1.f/819200.f),  f32);
        stout(outb, SCALAR_BASE + 2, acc[2] * (1.f/819200.f),  f32);
        stout(outb, SCALAR_BASE + 3, acc[3] * (1.f/1638400.f), f32);
    }
}

// ---------------------------------------------------------------------------
static inline void launch_gemm(hipStream_t st, int act, int transb,
                               const float* A, const void* Bw, size_t bwoff,
                               const void* bias, size_t biasoff,
                               const int* flg, float* C, int M, int N, int K) {
    // Big-tile path: VALU-bound 8x8 microtile. Requires K%16==0; use when the
    // grid stays big enough (N>=512 here means encoder/FFN GEMMs, grid>=400).
    if (N >= 512 && M >= 128 && (K & 15) == 0) {
        dim3 g((N + 127)/128, (M + 127)/128);
        if      (act == 0 && !transb) { gemm128_kernel<0,0,0><<<g,256,0,st>>>(A,Bw,bwoff,bias,biasoff,flg,C,M,N,K,K); return; }
        else if (act == 0 &&  transb) { gemm128_kernel<0,1,0><<<g,256,0,st>>>(A,Bw,bwoff,bias,biasoff,flg,C,M,N,K,K); return; }
        else if (act == 1 &&  transb) { gemm128_kernel<1,1,0><<<g,256,0,st>>>(A,Bw,bwoff,bias,biasoff,flg,C,M,N,K,K); return; }
    }
    dim3 g((N + 63)/64, (M + 63)/64);
    if      (act == 0 && !transb) gemm_kernel<0,0><<<g,256,0,st>>>(A,Bw,bwoff,bias,biasoff,flg,C,M,N,K);
    else if (act == 0 &&  transb) gemm_kernel<0,1><<<g,256,0,st>>>(A,Bw,bwoff,bias,biasoff,flg,C,M,N,K);
    else if (act == 1)            gemm_kernel<1,1><<<g,256,0,st>>>(A,Bw,bwoff,bias,biasoff,flg,C,M,N,K);
    else                          gemm_kernel<2,0><<<g,256,0,st>>>(A,Bw,bwoff,bias,biasoff,flg,C,M,N,K);
}

extern "C" void kernel_launch(void* const* d_in, const int* in_sizes, int n_in,
                              void* d_out, int out_size, void* d_ws, size_t ws_size,
                              hipStream_t stream) {
    const void* x      = d_in[0];
    const void* emb_w  = d_in[1];
    const void* Wq     = d_in[2];
    const void* Wk     = d_in[3];
    const void* Wv     = d_in[4];
    const void* Wo     = d_in[5];
    const void* bq     = d_in[6];
    const void* bk     = d_in[7];
    const void* bv     = d_in[8];
    const void* bo     = d_in[9];
    const void* c1w    = d_in[10];
    const void* c1b    = d_in[11];
    const void* c2w    = d_in[12];
    const void* c2b    = d_in[13];
    const void* ln1g   = d_in[14];
    const void* ln1b   = d_in[15];
    const void* ln2g   = d_in[16];
    const void* ln2b   = d_in[17];
    const void* lnfg   = d_in[18];
    const void* lnfb   = d_in[19];
    const void* en2de_w= d_in[20];
    const void* en2de_b= d_in[21];
    const void* eh1w   = d_in[22];
    const void* eh1b   = d_in[23];
    const void* eh2w   = d_in[24];
    const void* eh2b   = d_in[25];
    const void* mamw   = d_in[26];
    const void* mamb   = d_in[27];
    const void* malvw  = d_in[28];
    const void* malvb  = d_in[29];
    const void* zmw    = d_in[30];
    const void* zmb    = d_in[31];
    const void* zlvw   = d_in[32];
    const void* zlvb   = d_in[33];
    const void* dzm1w  = d_in[34];
    const void* dzm1b  = d_in[35];
    const void* dzm2w  = d_in[36];
    const void* dzm2b  = d_in[37];
    const void* dzl1w  = d_in[38];
    const void* dzl1b  = d_in[39];
    const void* dzl2w  = d_in[40];
    const void* dzl2b  = d_in[41];
    const void* dxm1w  = d_in[42];
    const void* dxm1b  = d_in[43];
    const void* dxm2w  = d_in[44];
    const void* dxm2b  = d_in[45];
    const void* otw    = d_in[46];
    const void* otb    = d_in[47];
    const void* theta  = d_in[48];
    const void* projw  = d_in[49];
    const void* projb  = d_in[50];

    float* ws = (float*)d_ws;
    const size_t NBUF = (size_t)NTOK * DM_;
    float* acc = ws;                                 // acc[0..6] + flag at [7]
    const int* flg = (const int*)ws + 7;
    float* h  = ws + 16;
    float* q  = h + NBUF;
    float* kb = h + 2*NBUF;
    float* vb = h + 3*NBUF;
    float* hv    = q;
    float* h1    = q  + 1638400;
    float* h2    = q  + 3276800;
    float* ma    = q  + 4915200;
    float* malv  = q  + 5734400;
    float* hb    = kb;
    float* zmean = kb + 2457600;
    float* zlvB  = kb + 4096000;
    float* pmb   = kb + 5734400;
    float* embv  = vb;
    float* t1    = vb + 819200;
    float* dzmB  = vb + 2457600;
    float* dzlB  = vb + 4096000;
    float* dxmB  = h;
    float* outf  = h + 1638400;

    init_kernel<<<1, 64, 0, stream>>>(ln1g, acc);
    embed_kernel<<<NTOK, 512, 0, stream>>>(x, emb_w, flg, h);

    for (int l = 0; l < L_; ++l) {
        const size_t WOFF = (size_t)l * DM_ * DM_;
        const size_t BOFF = (size_t)l * DM_;
        launch_gemm(stream, 0, 0, h, Wq, WOFF, bq, BOFF, flg, q,  NTOK, DM_, DM_);
        launch_gemm(stream, 0, 0, h, Wk, WOFF, bk, BOFF, flg, kb, NTOK, DM_, DM_);
        launch_gemm(stream, 0, 0, h, Wv, WOFF, bv, BOFF, flg, vb, NTOK, DM_, DM_);
        // independent series path (reads q/kb BEFORE attn overwrites q)
        dim3 sg(T_, H_, B_);
        series_kernel<<<sg, 128, 0, stream>>>(q, kb, d_out,
            (size_t)OUT_N + (size_t)l * SER_PER_L, flg);
        dim3 ag(H_, B_);
        attn_kernel<<<ag, 256, 0, stream>>>(q, kb, vb, q);
        launch_gemm(stream, 0, 0, q, Wo, WOFF, bo, BOFF, flg, kb, NTOK, DM_, DM_);
        ln_kernel<<<NTOK, 256, 0, stream>>>(h, kb, ln1g, ln1b, BOFF, flg);
        launch_gemm(stream, 1, 1, h, c1w, WOFF, c1b, BOFF, flg, q,  NTOK, DM_, DM_);
        launch_gemm(stream, 0, 1, q, c2w, WOFF, c2b, BOFF, flg, kb, NTOK, DM_, DM_);
        ln_kernel<<<NTOK, 256, 0, stream>>>(h, kb, ln2g, ln2b, BOFF, flg);
    }
    ln_kernel<<<NTOK, 256, 0, stream>>>(h, nullptr, lnfg, lnfb, 0, flg);

    launch_gemm(stream, 0, 0, h,  en2de_w, 0, en2de_b, 0, flg, hv, NTOK, 128, 512);
    launch_gemm(stream, 0, 0, hv, eh1w, 0, eh1b, 0, flg, h1, NTOK, 128, 128);
    launch_gemm(stream, 0, 0, h1, eh2w, 0, eh2b, 0, flg, h2, NTOK, 128, 128);
    launch_gemm(stream, 0, 0, h2, mamw, 0, mamb, 0, flg, ma,   NTOK, 64, 128);
    launch_gemm(stream, 0, 0, h2, malvw, 0, malvb, 0, flg, malv, NTOK, 64, 128);
    concat_kernel<<<(NTOK*192 + 255)/256, 256, 0, stream>>>(h1, ma, hb, NTOK*192);
    launch_gemm(stream, 0, 0, hb, zmw, 0, zmb, 0, flg, zmean, NTOK, 128, 192);
    launch_gemm(stream, 0, 0, hb, zlvw, 0, zlvb, 0, flg, zlvB,  NTOK, 128, 192);
    launch_gemm(stream, 0, 0, ma, otw, 0, otb, 0, flg, pmb, NTOK, 64, 64);
    ot_kernel<<<NTOK, 64, 0, stream>>>(pmb, theta, flg, embv, acc);
    launch_gemm(stream, 2, 0, embv, dzm1w, 0, dzm1b, 0, flg, t1, NTOK, 128, 64);
    launch_gemm(stream, 0, 0, t1, dzm2w, 0, dzm2b, 0, flg, dzmB, NTOK, 128, 128);
    launch_gemm(stream, 2, 0, embv, dzl1w, 0, dzl1b, 0, flg, t1, NTOK, 128, 64);
    launch_gemm(stream, 0, 0, t1, dzl2w, 0, dzl2b, 0, flg, dzlB, NTOK, 128, 128);
    launch_gemm(stream, 2, 0, zmean, dxm1w, 0, dxm1b, 0, flg, t1, NTOK, 128, 128);
    launch_gemm(stream, 0, 0, t1, dxm2w, 0, dxm2b, 0, flg, dxmB, NTOK, 128, 128);
    klc_kernel<<<256, 256, 0, stream>>>(ma, malv, acc);
    klz_kernel<<<256, 256, 0, stream>>>(dzmB, zmean, zlvB, dzlB, acc);
    // Final projection: split-K with the big-tile kernel.
    // Grid 30x1x16 = 480 blocks; each block does an 800-deep K-chunk.
    proj_init_kernel<<<(OUT_N + 255)/256, 256, 0, stream>>>(projb, flg, outf);
    {
        dim3 pg((3800 + 127)/128, 1, PROJ_KS);
        gemm128_kernel<0,0,1><<<pg, 256, 0, stream>>>(dxmB, projw, 0, nullptr, 0,
                                                      flg, outf, B_, 3800, 12800,
                                                      12800/PROJ_KS);
    }
    finalize_kernel<<<(OUT_N + 255)/256, 256, 0, stream>>>(outf, acc, d_out);
}

// Round 3
// 4411.752 us; speedup vs baseline: 1.7445x; 1.7445x over previous
//
#include <hip/hip_runtime.h>
#include <hip/hip_bf16.h>
#include <math.h>

typedef __hip_bfloat16 bf16;
typedef unsigned int u32;

#define B_      128
#define T_      100
#define ENC_IN_ 38
#define DM_     512
#define H_      8
#define HD_     64
#define L_      3
#define NTOK    (B_*T_)      /* 12800 */
#define K_CB    50           /* codebook size */

#define OUT_N     486400      /* B*T*C_OUT */
#define SER_N     30720000    /* L*B*H*T*T */
#define SER_PER_L 10240000    /* B*H*T*T */
#define SCALAR_BASE (OUT_N + SER_N)   /* 31206400 */

#define PROJ_KS 16            /* split-K factor for the final projection GEMM */
#define WSEG    786432        /* 3*512*512 elements per prepped weight array */

// Dual-dtype input load: inputs are either all-f32 or all-bf16.
__device__ __forceinline__ float ldin(const void* p, size_t i, int f32) {
    if (f32) return ((const float*)p)[i];
    return __bfloat162float(((const bf16*)p)[i]);
}
__device__ __forceinline__ void stout(void* p, size_t i, float v, int f32) {
    if (f32) ((float*)p)[i] = v;
    else     ((bf16*)p)[i] = __float2bfloat16(v);
}

// bf16 split helpers (RNE round to bf16; lo = residual rounded to bf16)
__device__ __forceinline__ ushort bf_hi(float x) {
    union { float f; u32 u; } c; c.f = x;
    return (ushort)((c.u + 0x7FFFu + ((c.u >> 16) & 1u)) >> 16);
}
__device__ __forceinline__ float bf_f(ushort h) {
    union { float f; u32 u; } c; c.u = (u32)h << 16; return c.f;
}

typedef __attribute__((ext_vector_type(8))) short short8v;
typedef __attribute__((ext_vector_type(4))) float f32x4;

// ---------------------------------------------------------------------------
// init: zero scalar accumulators acc[0..6]; detect input dtype from ln1g.
// ---------------------------------------------------------------------------
__global__ void init_kernel(const void* ln1g, float* acc) {
    if (threadIdx.x < 7) acc[threadIdx.x] = 0.f;
    if (threadIdx.x == 7) {
        u32 w0 = *(const u32*)ln1g;
        ((int*)acc)[7] = (w0 == 0x3F800000u) ? 1 : 0;
    }
}

// ---------------------------------------------------------------------------
// Weight prep A: transpose + bf16-split. In: W dual-dtype [3][512 k][512 n].
// Out: hi/lo bf16 bits [3][512 n][512 k].
// ---------------------------------------------------------------------------
__launch_bounds__(256)
__global__ void prep_t_kernel(const void* __restrict__ W, const int* __restrict__ flg,
                              ushort* __restrict__ hi, ushort* __restrict__ lo) {
    __shared__ float t[32][33];
    const int k0 = blockIdx.x*32, n0 = blockIdx.y*32, l = blockIdx.z;
    const int c = threadIdx.x & 31, r = threadIdx.x >> 5;   // r 0..7
    const int f32 = flg[0];
    const size_t base = (size_t)l*512*512;
#pragma unroll
    for (int i = 0; i < 4; ++i)
        t[r + i*8][c] = ldin(W, base + (size_t)(k0 + r + i*8)*512 + n0 + c, f32);
    __syncthreads();
#pragma unroll
    for (int i = 0; i < 4; ++i) {
        int a = r + i*8;                 // n within tile
        float v = t[c][a];               // = W[k0+c][n0+a]
        ushort h = bf_hi(v);
        size_t o = base + (size_t)(n0 + a)*512 + k0 + c;
        hi[o] = h;
        lo[o] = bf_hi(v - bf_f(h));
    }
}

// ---------------------------------------------------------------------------
// Weight prep B: bf16-split only (weights already [out n][in k]).
// ---------------------------------------------------------------------------
__global__ void prep_s_kernel(const void* __restrict__ W, const int* __restrict__ flg,
                              ushort* __restrict__ hi, ushort* __restrict__ lo, int n) {
    int i = blockIdx.x*256 + threadIdx.x;
    if (i >= n) return;
    float v = ldin(W, i, flg[0]);
    ushort h = bf_hi(v);
    hi[i] = h;
    lo[i] = bf_hi(v - bf_f(h));
}

// ---------------------------------------------------------------------------
// Embedding: circular conv1d(k=3) + sinusoidal positions. Block per token.
// ---------------------------------------------------------------------------
__launch_bounds__(512)
__global__ void embed_kernel(const void* __restrict__ x, const void* __restrict__ w,
                             const int* __restrict__ flg, float* __restrict__ h) {
    __shared__ float xs[3*ENC_IN_];
    const int f32 = flg[0];
    const int blk = blockIdx.x;
    const int b = blk / T_, t = blk - b*T_;
    const int tid = threadIdx.x;
    if (tid < 3*ENC_IN_) {
        int wv = tid / ENC_IN_, c = tid - wv*ENC_IN_;
        int rr = t - 1 + wv; rr = (rr + T_) % T_;
        xs[tid] = ldin(x, ((size_t)b*T_ + rr)*ENC_IN_ + c, f32);
    }
    __syncthreads();
    int i2 = tid & ~1;
    float freq = expf(-(float)i2 * (9.210340371976184f / 512.f));
    float ang = (float)t * freq;
    float s = (tid & 1) ? cosf(ang) : sinf(ang);
    for (int j = 0; j < 3*ENC_IN_; ++j)
        s = fmaf(xs[j], ldin(w, (size_t)j*DM_ + tid, f32), s);
    h[(size_t)blk*DM_ + tid] = s;
}

// ---------------------------------------------------------------------------
// MFMA GEMM (bf16x3): C = act(A @ Bprep + bias). A f32 [M][K]; B pre-split
// bf16 hi/lo [N][K]. Tile 128x128, 4 waves (2x2), per-wave 4x4 fragments of
// 16x16x32. D = Ah*Bh + Al*Bh (+ Ah*Bl when inputs f32; bf16 mode: Bl==0,
// skipped). k-permutation of fragment layout cancels (A,B loaded identically);
// C/D mapping col=lane&15, row=(lane>>4)*4+reg [m89-verified].
// LDS pitch 40 bf16 -> frag ds_read_b128 hits each bank exactly 8x (even).
// Requires M%128==0, N%128==0, K%32==0.
// ---------------------------------------------------------------------------
#define PK 40
template<int ACT>
__launch_bounds__(256, 1)
__global__ void gemm_mfma_kernel(const float* __restrict__ A,
                                 const ushort* __restrict__ Bh,
                                 const ushort* __restrict__ Bl,
                                 const void* __restrict__ bias, size_t biasoff,
                                 const int* __restrict__ flg,
                                 float* __restrict__ C, int M, int N, int K) {
    __shared__ ushort sAh[128*PK];
    __shared__ ushort sAl[128*PK];
    __shared__ ushort sBh[128*PK];
    __shared__ ushort sBl[128*PK];
    const int tid = threadIdx.x;
    const int lane = tid & 63, wid = tid >> 6;
    const int wr = wid >> 1, wc = wid & 1;
    const int m0 = blockIdx.y * 128, n0 = blockIdx.x * 128;
    const int useBl = flg[0];
    const int r  = tid >> 1;
    const int ks = (tid & 1) * 16;
    const float*  Ap  = A  + (size_t)(m0 + r)*K + ks;
    const ushort* Bhp = Bh + (size_t)(n0 + r)*K + ks;
    const ushort* Blp = Bl + (size_t)(n0 + r)*K + ks;
    const int frow = lane & 15, fk = (lane >> 4) * 8;
    const f32x4 zero = {0.f, 0.f, 0.f, 0.f};
    f32x4 acc[4][4];
#pragma unroll
    for (int m = 0; m < 4; ++m)
#pragma unroll
        for (int n = 0; n < 4; ++n) acc[m][n] = zero;

    for (int k0 = 0; k0 < K; k0 += 32) {
#pragma unroll
        for (int j = 0; j < 4; ++j) {
            float4 v = *(const float4*)(Ap + k0 + j*4);
            ushort4 hi, lo;
            hi.x = bf_hi(v.x); lo.x = bf_hi(v.x - bf_f(hi.x));
            hi.y = bf_hi(v.y); lo.y = bf_hi(v.y - bf_f(hi.y));
            hi.z = bf_hi(v.z); lo.z = bf_hi(v.z - bf_f(hi.z));
            hi.w = bf_hi(v.w); lo.w = bf_hi(v.w - bf_f(hi.w));
            *(ushort4*)&sAh[r*PK + ks + j*4] = hi;
            *(ushort4*)&sAl[r*PK + ks + j*4] = lo;
        }
        *(uint4*)&sBh[r*PK + ks]     = *(const uint4*)(Bhp + k0);
        *(uint4*)&sBh[r*PK + ks + 8] = *(const uint4*)(Bhp + k0 + 8);
        if (useBl) {
            *(uint4*)&sBl[r*PK + ks]     = *(const uint4*)(Blp + k0);
            *(uint4*)&sBl[r*PK + ks + 8] = *(const uint4*)(Blp + k0 + 8);
        }
        __syncthreads();
        short8v ah[4], al[4], bh[4];
#pragma unroll
        for (int m = 0; m < 4; ++m) {
            int row = wr*64 + m*16 + frow;
            ah[m] = *(const short8v*)&sAh[row*PK + fk];
            al[m] = *(const short8v*)&sAl[row*PK + fk];
        }
#pragma unroll
        for (int n = 0; n < 4; ++n) {
            int col = wc*64 + n*16 + frow;
            bh[n] = *(const short8v*)&sBh[col*PK + fk];
        }
#pragma unroll
        for (int m = 0; m < 4; ++m)
#pragma unroll
            for (int n = 0; n < 4; ++n) {
                acc[m][n] = __builtin_amdgcn_mfma_f32_16x16x32_bf16(ah[m], bh[n], acc[m][n], 0, 0, 0);
                acc[m][n] = __builtin_amdgcn_mfma_f32_16x16x32_bf16(al[m], bh[n], acc[m][n], 0, 0, 0);
            }
        if (useBl) {
            short8v bl[4];
#pragma unroll
            for (int n = 0; n < 4; ++n) {
                int col = wc*64 + n*16 + frow;
                bl[n] = *(const short8v*)&sBl[col*PK + fk];
            }
#pragma unroll
            for (int m = 0; m < 4; ++m)
#pragma unroll
                for (int n = 0; n < 4; ++n)
                    acc[m][n] = __builtin_amdgcn_mfma_f32_16x16x32_bf16(ah[m], bl[n], acc[m][n], 0, 0, 0);
        }
        __syncthreads();
    }
    const int f32b = flg[0];
#pragma unroll
    for (int m = 0; m < 4; ++m) {
        int row0 = m0 + wr*64 + m*16 + (lane >> 4)*4;
#pragma unroll
        for (int n = 0; n < 4; ++n) {
            int col = n0 + wc*64 + n*16 + (lane & 15);
            float bv = bias ? ldin(bias, biasoff + col, f32b) : 0.f;
#pragma unroll
            for (int i = 0; i < 4; ++i) {
                float vv = acc[m][n][i] + bv;
                if (ACT == 1) vv = 0.5f*vv*(1.f + erff(vv*0.7071067811865475f));
                C[(size_t)(row0 + i)*N + col] = vv;
            }
        }
    }
}

// ---------------------------------------------------------------------------
// Generic small GEMM: 64x64 tile, 256 threads, 4x4 microtile (decoder smalls).
// ---------------------------------------------------------------------------
template<int ACT, int TRANSB>
__launch_bounds__(256)
__global__ void gemm_kernel(const float* __restrict__ A, const void* __restrict__ Bw,
                            size_t bwoff, const void* __restrict__ bias, size_t biasoff,
                            const int* __restrict__ flg,
                            float* __restrict__ C, int M, int N, int K) {
    __shared__ float As[16][68];
    __shared__ float Bs[16][68];
    const int f32 = flg[0];
    const int tid = threadIdx.x;
    const int tx = tid & 15, ty = tid >> 4;
    const int m0 = blockIdx.y * 64, n0 = blockIdx.x * 64;
    float acc[4][4] = {};
    for (int k0 = 0; k0 < K; k0 += 16) {
        for (int i = tid; i < 1024; i += 256) {
            int r = i >> 4, kk = i & 15;
            int gm = m0 + r, gk = k0 + kk;
            As[kk][r] = (gm < M && gk < K) ? A[(size_t)gm*K + gk] : 0.f;
        }
        for (int i = tid; i < 1024; i += 256) {
            int kk, c;
            if (TRANSB) { c = i >> 4; kk = i & 15; }
            else        { kk = i >> 6; c = i & 63; }
            int gk = k0 + kk, gn = n0 + c;
            float vv = 0.f;
            if (gk < K && gn < N)
                vv = TRANSB ? ldin(Bw, bwoff + (size_t)gn*K + gk, f32)
                            : ldin(Bw, bwoff + (size_t)gk*N + gn, f32);
            Bs[kk][c] = vv;
        }
        __syncthreads();
#pragma unroll
        for (int kk = 0; kk < 16; ++kk) {
            float4 av = *(const float4*)&As[kk][ty*4];
            float4 bv = *(const float4*)&Bs[kk][tx*4];
            float a[4] = {av.x, av.y, av.z, av.w};
            float b[4] = {bv.x, bv.y, bv.z, bv.w};
#pragma unroll
            for (int ii = 0; ii < 4; ++ii)
#pragma unroll
                for (int jj = 0; jj < 4; ++jj)
                    acc[ii][jj] = fmaf(a[ii], b[jj], acc[ii][jj]);
        }
        __syncthreads();
    }
#pragma unroll
    for (int ii = 0; ii < 4; ++ii) {
        int gm = m0 + ty*4 + ii;
        if (gm >= M) continue;
#pragma unroll
        for (int jj = 0; jj < 4; ++jj) {
            int gn = n0 + tx*4 + jj;
            if (gn >= N) continue;
            float vv = acc[ii][jj] + (bias ? ldin(bias, biasoff + gn, f32) : 0.f);
            if (ACT == 1) vv = 0.5f * vv * (1.f + erff(vv * 0.7071067811865475f));
            if (ACT == 2) vv = fmaxf(vv, 0.f);
            C[(size_t)gm*N + gn] = vv;
        }
    }
}

// ---------------------------------------------------------------------------
// Round-1 split-K projection GEMM (known good: 447us @ 53% occupancy).
// ---------------------------------------------------------------------------
__launch_bounds__(256)
__global__ void proj_init_kernel(const void* __restrict__ bias,
                                 const int* __restrict__ flg,
                                 float* __restrict__ C) {
    int i = blockIdx.x*256 + threadIdx.x;
    if (i < OUT_N) C[i] = ldin(bias, (size_t)(i % 3800), flg[0]);
}

__launch_bounds__(256)
__global__ void proj_gemm_kernel(const float* __restrict__ A, const void* __restrict__ Bw,
                                 const int* __restrict__ flg, float* __restrict__ C,
                                 int M, int N, int K, int kchunk) {
    __shared__ float As[16][68];
    __shared__ float Bs[16][68];
    const int f32 = flg[0];
    const int tid = threadIdx.x;
    const int tx = tid & 15, ty = tid >> 4;
    const int m0 = blockIdx.y * 64, n0 = blockIdx.x * 64;
    const int kbeg = blockIdx.z * kchunk;
    const int kend = kbeg + kchunk;
    float acc[4][4] = {};
    for (int k0 = kbeg; k0 < kend; k0 += 16) {
        for (int i = tid; i < 1024; i += 256) {
            int r = i >> 4, kk = i & 15;
            int gm = m0 + r;
            As[kk][r] = (gm < M) ? A[(size_t)gm*K + (k0 + kk)] : 0.f;
        }
        for (int i = tid; i < 1024; i += 256) {
            int kk = i >> 6, c = i & 63;
            int gn = n0 + c;
            Bs[kk][c] = (gn < N) ? ldin(Bw, (size_t)(k0 + kk)*N + gn, f32) : 0.f;
        }
        __syncthreads();
#pragma unroll
        for (int kk = 0; kk < 16; ++kk) {
            float4 av = *(const float4*)&As[kk][ty*4];
            float4 bv = *(const float4*)&Bs[kk][tx*4];
            float a[4] = {av.x, av.y, av.z, av.w};
            float b[4] = {bv.x, bv.y, bv.z, bv.w};
#pragma unroll
            for (int ii = 0; ii < 4; ++ii)
#pragma unroll
                for (int jj = 0; jj < 4; ++jj)
                    acc[ii][jj] = fmaf(a[ii], b[jj], acc[ii][jj]);
        }
        __syncthreads();
    }
#pragma unroll
    for (int ii = 0; ii < 4; ++ii) {
        int gm = m0 + ty*4 + ii;
        if (gm >= M) continue;
#pragma unroll
        for (int jj = 0; jj < 4; ++jj) {
            int gn = n0 + tx*4 + jj;
            if (gn >= N) continue;
            atomicAdd(&C[(size_t)gm*N + gn], acc[ii][jj]);
        }
    }
}

// ---------------------------------------------------------------------------
// Series kernel: one block per (b, h, t) query row.
// ---------------------------------------------------------------------------
__launch_bounds__(128)
__global__ void series_kernel(const float* __restrict__ Q, const float* __restrict__ Kg,
                              void* __restrict__ outb, size_t soff,
                              const int* __restrict__ flg) {
    __shared__ float qs[64];
    __shared__ float red[128];
    const int t = blockIdx.x, hh = blockIdx.y, b = blockIdx.z;
    const int tid = threadIdx.x;
    const size_t base = (size_t)b*T_*DM_ + (size_t)hh*HD_;
    if (tid < 64) qs[tid] = Q[base + (size_t)t*DM_ + tid];
    __syncthreads();
    float lg = -1e30f;
    if (tid < T_) {
        const float* kr = Kg + base + (size_t)tid*DM_;
        float dot = 0.f;
#pragma unroll 8
        for (int d = 0; d < 64; ++d) dot = fmaf(qs[d], kr[d], dot);
        lg = dot * 0.125f;
    }
    red[tid] = lg;
    __syncthreads();
    for (int st = 64; st > 0; st >>= 1) { if (tid < st) red[tid] = fmaxf(red[tid], red[tid+st]); __syncthreads(); }
    const float mx = red[0];
    __syncthreads();
    float e = (tid < T_) ? expf(lg - mx) : 0.f;
    red[tid] = e;
    __syncthreads();
    for (int st = 64; st > 0; st >>= 1) { if (tid < st) red[tid] += red[tid+st]; __syncthreads(); }
    const float inv = 1.f / red[0];
    if (tid < T_)
        stout(outb, soff + ((size_t)(b*H_ + hh)*T_ + t)*T_ + tid, e * inv, flg[0]);
}

// ---------------------------------------------------------------------------
// Fused attention context for one (b, head): C = softmax(0.125 Q K^T) V.
// ---------------------------------------------------------------------------
__launch_bounds__(256)
__global__ void attn_kernel(const float* Q, const float* __restrict__ Kg,
                            const float* __restrict__ Vg, float* Cg) {
    __shared__ float Ks[T_*65];
    __shared__ float Vs[T_*65];
    __shared__ float Qrow[4][64];
    __shared__ float Prow[4][104];
    const int tid = threadIdx.x;
    const int lane = tid & 63, w = tid >> 6;
    const int hh = blockIdx.x, b = blockIdx.y;
    const size_t base = (size_t)b*T_*DM_ + (size_t)hh*HD_;
    for (int i = tid; i < T_*HD_; i += 256) {
        int r = i >> 6, d = i & 63;
        size_t g = base + (size_t)r*DM_ + d;
        Ks[r*65+d] = Kg[g];
        Vs[r*65+d] = Vg[g];
    }
    __syncthreads();
    for (int i = 0; i < 25; ++i) {
        const int t = i*4 + w;
        Qrow[w][lane] = Q[base + (size_t)t*DM_ + lane];
        __syncthreads();
        const int s2 = 64 + lane;
        float acc1 = 0.f, acc2 = 0.f;
#pragma unroll 16
        for (int d = 0; d < 64; ++d) {
            float qd = Qrow[w][d];
            acc1 = fmaf(qd, Ks[lane*65 + d], acc1);
            if (s2 < T_) acc2 = fmaf(qd, Ks[s2*65 + d], acc2);
        }
        acc1 *= 0.125f; acc2 *= 0.125f;
        float mx = (s2 < T_) ? fmaxf(acc1, acc2) : acc1;
        for (int off = 32; off > 0; off >>= 1) mx = fmaxf(mx, __shfl_xor(mx, off));
        float e1 = expf(acc1 - mx);
        float e2 = (s2 < T_) ? expf(acc2 - mx) : 0.f;
        float sum = e1 + e2;
        for (int off = 32; off > 0; off >>= 1) sum += __shfl_xor(sum, off);
        float inv = 1.f / sum;
        Prow[w][lane] = e1 * inv;
        if (s2 < T_) Prow[w][s2] = e2 * inv;
        __syncthreads();
        float o = 0.f;
#pragma unroll 10
        for (int s = 0; s < T_; ++s)
            o = fmaf(Prow[w][s], Vs[s*65 + lane], o);
        Cg[base + (size_t)t*DM_ + lane] = o;
    }
}

// ---------------------------------------------------------------------------
// Residual + LayerNorm over 512 dims; in-place on h.
// ---------------------------------------------------------------------------
__launch_bounds__(256)
__global__ void ln_kernel(float* __restrict__ h, const float* __restrict__ res,
                          const void* __restrict__ g, const void* __restrict__ bta,
                          size_t goff, const int* __restrict__ flg) {
    __shared__ float red[256];
    const int f32 = flg[0];
    const int row = blockIdx.x, tid = threadIdx.x;
    float* hp = h + (size_t)row*DM_;
    float x0 = hp[tid], x1 = hp[tid+256];
    if (res) {
        x0 += res[(size_t)row*DM_ + tid];
        x1 += res[(size_t)row*DM_ + tid + 256];
    }
    red[tid] = x0 + x1;
    __syncthreads();
    for (int s = 128; s > 0; s >>= 1) { if (tid < s) red[tid] += red[tid+s]; __syncthreads(); }
    float mean = red[0] * (1.f/512.f);
    __syncthreads();
    float d0 = x0 - mean, d1 = x1 - mean;
    red[tid] = d0*d0 + d1*d1;
    __syncthreads();
    for (int s = 128; s > 0; s >>= 1) { if (tid < s) red[tid] += red[tid+s]; __syncthreads(); }
    float rs = 1.f / sqrtf(red[0]*(1.f/512.f) + 1e-5f);
    hp[tid]     = d0*rs*ldin(g, goff+tid, f32)     + ldin(bta, goff+tid, f32);
    hp[tid+256] = d1*rs*ldin(g, goff+tid+256, f32) + ldin(bta, goff+tid+256, f32);
}

// ---------------------------------------------------------------------------
__global__ void concat_kernel(const float* __restrict__ h1, const float* __restrict__ ma,
                              float* __restrict__ hb, int n) {
    int i = blockIdx.x*blockDim.x + threadIdx.x;
    if (i >= n) return;
    int row = i / 192, j = i - row*192;
    hb[i] = (j < 128) ? h1[(size_t)row*128 + j] : ma[(size_t)row*64 + (j-128)];
}

// ---------------------------------------------------------------------------
// OT concept head, one block (64 threads) per token.
// ---------------------------------------------------------------------------
__launch_bounds__(64)
__global__ void ot_kernel(const float* __restrict__ pm, const void* __restrict__ theta,
                          const int* __restrict__ flg,
                          float* __restrict__ embv, float* __restrict__ acc) {
    __shared__ float th[K_CB*64];
    __shared__ float pmv[64];
    __shared__ float red[64];
    __shared__ float pvec[64];
    const int f32 = flg[0];
    const int tid = threadIdx.x;
    const int tok = blockIdx.x;
    for (int i = tid; i < K_CB*64; i += 64) th[i] = ldin(theta, i, f32);
    pmv[tid] = pm[(size_t)tok*64 + tid];
    __syncthreads();
    red[tid] = pmv[tid]*pmv[tid];
    __syncthreads();
    for (int s = 32; s > 0; s >>= 1) { if (tid < s) red[tid] += red[tid+s]; __syncthreads(); }
    float pm2 = red[0];
    __syncthreads();
    float cost = 0.f;
    if (tid < K_CB) {
        const float* tr = th + tid*64;
        float dot = 0.f, t2 = 0.f;
        for (int d = 0; d < 64; ++d) { float tv = tr[d]; dot = fmaf(pmv[d], tv, dot); t2 = fmaf(tv, tv, t2); }
        cost = pm2 - 2.f*dot + t2;
    }
    float logit = (tid < K_CB) ? (-cost / 0.1f) : -1e30f;
    red[tid] = logit;
    __syncthreads();
    for (int s = 32; s > 0; s >>= 1) { if (tid < s) red[tid] = fmaxf(red[tid], red[tid+s]); __syncthreads(); }
    float mx = red[0];
    __syncthreads();
    float e = (tid < K_CB) ? expf(logit - mx) : 0.f;
    red[tid] = e;
    __syncthreads();
    for (int s = 32; s > 0; s >>= 1) { if (tid < s) red[tid] += red[tid+s]; __syncthreads(); }
    float p = e / red[0];
    __syncthreads();
    pvec[tid] = p;
    red[tid] = p * cost;
    __syncthreads();
    for (int s = 32; s > 0; s >>= 1) { if (tid < s) red[tid] += red[tid+s]; __syncthreads(); }
    if (tid == 0) atomicAdd(acc + 0, red[0]);
    __syncthreads();
    float eb = 0.f;
    for (int kk = 0; kk < K_CB; ++kk) eb = fmaf(pvec[kk], th[kk*64 + tid], eb);
    embv[(size_t)tok*64 + tid] = eb;
    float dd = eb - pmv[tid];
    red[tid] = dd*dd;
    __syncthreads();
    for (int s = 32; s > 0; s >>= 1) { if (tid < s) red[tid] += red[tid+s]; __syncthreads(); }
    if (tid == 0) atomicAdd(acc + 1, red[0]);
}

// ---------------------------------------------------------------------------
__global__ void klc_kernel(const float* __restrict__ m, const float* __restrict__ lv,
                           float* __restrict__ acc) {
    __shared__ float red[256];
    const int tid = threadIdx.x;
    float s = 0.f;
    for (int i = blockIdx.x*256 + tid; i < NTOK*64; i += gridDim.x*256) {
        float mm = m[i], l = lv[i];
        s += -0.5f * (1.f - mm*mm + l - expf(l));
    }
    red[tid] = s; __syncthreads();
    for (int st = 128; st > 0; st >>= 1) { if (tid < st) red[tid] += red[tid+st]; __syncthreads(); }
    if (tid == 0) atomicAdd(acc + 2, red[0]);
}

__global__ void klz_kernel(const float* __restrict__ dzm, const float* __restrict__ zm,
                           const float* __restrict__ zlv, const float* __restrict__ dzl,
                           float* __restrict__ acc) {
    __shared__ float red[256];
    const int tid = threadIdx.x;
    float s = 0.f;
    for (int i = blockIdx.x*256 + tid; i < NTOK*128; i += gridDim.x*256) {
        float d = dzm[i] - zm[i];
        float zl = zlv[i], dl = dzl[i];
        s += 0.5f * (d*d / expf(zl) + expf(dl - zl) - 1.f - (dl - zl));
    }
    red[tid] = s; __syncthreads();
    for (int st = 128; st > 0; st >>= 1) { if (tid < st) red[tid] += red[tid+st]; __syncthreads(); }
    if (tid == 0) atomicAdd(acc + 3, red[0]);
}

// ---------------------------------------------------------------------------
__global__ void finalize_kernel(const float* __restrict__ outf, const float* __restrict__ acc,
                                void* __restrict__ outb) {
    const int f32 = ((const int*)acc)[7];
    int i = blockIdx.x*blockDim.x + threadIdx.x;
    if (i < OUT_N) stout(outb, i, outf[i], f32);
    if (i == 0) {
        stout(outb, SCALAR_BASE + 0, acc[0] * (1.f/12800.f),   f32);
        stout(outb, SCALAR_BASE + 1, acc[1] * (1.f/819200.f),  f32);
        stout(outb, SCALAR_BASE + 2, acc[2] * (1.f/819200.f),  f32);
        stout(outb, SCALAR_BASE + 3, acc[3] * (1.f/1638400.f), f32);
    }
}

// ---------------------------------------------------------------------------
static inline void launch_gemm(hipStream_t st, int act, int transb,
                               const float* A, const void* Bw, size_t bwoff,
                               const void* bias, size_t biasoff,
                               const int* flg, float* C, int M, int N, int K) {
    dim3 g((N + 63)/64, (M + 63)/64);
    if      (act == 0 && !transb) gemm_kernel<0,0><<<g,256,0,st>>>(A,Bw,bwoff,bias,biasoff,flg,C,M,N,K);
    else if (act == 0 &&  transb) gemm_kernel<0,1><<<g,256,0,st>>>(A,Bw,bwoff,bias,biasoff,flg,C,M,N,K);
    else if (act == 1)            gemm_kernel<1,1><<<g,256,0,st>>>(A,Bw,bwoff,bias,biasoff,flg,C,M,N,K);
    else                          gemm_kernel<2,0><<<g,256,0,st>>>(A,Bw,bwoff,bias,biasoff,flg,C,M,N,K);
}

extern "C" void kernel_launch(void* const* d_in, const int* in_sizes, int n_in,
                              void* d_out, int out_size, void* d_ws, size_t ws_size,
                              hipStream_t stream) {
    const void* x      = d_in[0];
    const void* emb_w  = d_in[1];
    const void* Wq     = d_in[2];
    const void* Wk     = d_in[3];
    const void* Wv     = d_in[4];
    const void* Wo     = d_in[5];
    const void* bq     = d_in[6];
    const void* bk     = d_in[7];
    const void* bv     = d_in[8];
    const void* bo     = d_in[9];
    const void* c1w    = d_in[10];
    const void* c1b    = d_in[11];
    const void* c2w    = d_in[12];
    const void* c2b    = d_in[13];
    const void* ln1g   = d_in[14];
    const void* ln1b   = d_in[15];
    const void* ln2g   = d_in[16];
    const void* ln2b   = d_in[17];
    const void* lnfg   = d_in[18];
    const void* lnfb   = d_in[19];
    const void* en2de_w= d_in[20];
    const void* en2de_b= d_in[21];
    const void* eh1w   = d_in[22];
    const void* eh1b   = d_in[23];
    const void* eh2w   = d_in[24];
    const void* eh2b   = d_in[25];
    const void* mamw   = d_in[26];
    const void* mamb   = d_in[27];
    const void* malvw  = d_in[28];
    const void* malvb  = d_in[29];
    const void* zmw    = d_in[30];
    const void* zmb    = d_in[31];
    const void* zlvw   = d_in[32];
    const void* zlvb   = d_in[33];
    const void* dzm1w  = d_in[34];
    const void* dzm1b  = d_in[35];
    const void* dzm2w  = d_in[36];
    const void* dzm2b  = d_in[37];
    const void* dzl1w  = d_in[38];
    const void* dzl1b  = d_in[39];
    const void* dzl2w  = d_in[40];
    const void* dzl2b  = d_in[41];
    const void* dxm1w  = d_in[42];
    const void* dxm1b  = d_in[43];
    const void* dxm2w  = d_in[44];
    const void* dxm2b  = d_in[45];
    const void* otw    = d_in[46];
    const void* otb    = d_in[47];
    const void* theta  = d_in[48];
    const void* projw  = d_in[49];
    const void* projb  = d_in[50];

    float* ws = (float*)d_ws;
    const size_t NBUF = (size_t)NTOK * DM_;
    float* acc = ws;                                 // acc[0..6] + flag at [7]
    const int* flg = (const int*)ws + 7;
    float* h  = ws + 16;
    float* q  = h + NBUF;
    float* kb = h + 2*NBUF;
    float* vb = h + 3*NBUF;
    float* hv    = q;
    float* h1    = q  + 1638400;
    float* h2    = q  + 3276800;
    float* ma    = q  + 4915200;
    float* malv  = q  + 5734400;
    float* hb    = kb;
    float* zmean = kb + 2457600;
    float* zlvB  = kb + 4096000;
    float* pmb   = kb + 5734400;
    float* embv  = vb;
    float* t1    = vb + 819200;
    float* dzmB  = vb + 2457600;
    float* dzlB  = vb + 4096000;
    float* dxmB  = h;
    float* outf  = h + 1638400;
    // pre-split bf16 weight region beyond the 4 NBUF f32 buffers (18.9 MB)
    ushort* wp  = (ushort*)(vb + NBUF);
    ushort* wqh = wp;            ushort* wql = wp + 1*(size_t)WSEG;
    ushort* wkh = wp + 2*(size_t)WSEG;   ushort* wkl = wp + 3*(size_t)WSEG;
    ushort* wvh = wp + 4*(size_t)WSEG;   ushort* wvl = wp + 5*(size_t)WSEG;
    ushort* woh = wp + 6*(size_t)WSEG;   ushort* wol = wp + 7*(size_t)WSEG;
    ushort* c1h = wp + 8*(size_t)WSEG;   ushort* c1l = wp + 9*(size_t)WSEG;
    ushort* c2h = wp + 10*(size_t)WSEG;  ushort* c2l = wp + 11*(size_t)WSEG;

    init_kernel<<<1, 64, 0, stream>>>(ln1g, acc);
    {
        dim3 tg(16, 16, 3);
        prep_t_kernel<<<tg, 256, 0, stream>>>(Wq, flg, wqh, wql);
        prep_t_kernel<<<tg, 256, 0, stream>>>(Wk, flg, wkh, wkl);
        prep_t_kernel<<<tg, 256, 0, stream>>>(Wv, flg, wvh, wvl);
        prep_t_kernel<<<tg, 256, 0, stream>>>(Wo, flg, woh, wol);
        prep_s_kernel<<<(WSEG + 255)/256, 256, 0, stream>>>(c1w, flg, c1h, c1l, WSEG);
        prep_s_kernel<<<(WSEG + 255)/256, 256, 0, stream>>>(c2w, flg, c2h, c2l, WSEG);
    }
    embed_kernel<<<NTOK, 512, 0, stream>>>(x, emb_w, flg, h);

    const dim3 mg(4, 100);   // N=512 -> 4 tiles, M=12800 -> 100 tiles
    for (int l = 0; l < L_; ++l) {
        const size_t PW = (size_t)l * DM_ * DM_;
        const size_t BOFF = (size_t)l * DM_;
        gemm_mfma_kernel<0><<<mg, 256, 0, stream>>>(h, wqh+PW, wql+PW, bq, BOFF, flg, q,  NTOK, DM_, DM_);
        gemm_mfma_kernel<0><<<mg, 256, 0, stream>>>(h, wkh+PW, wkl+PW, bk, BOFF, flg, kb, NTOK, DM_, DM_);
        gemm_mfma_kernel<0><<<mg, 256, 0, stream>>>(h, wvh+PW, wvl+PW, bv, BOFF, flg, vb, NTOK, DM_, DM_);
        // independent series path (reads q/kb BEFORE attn overwrites q)
        dim3 sg(T_, H_, B_);
        series_kernel<<<sg, 128, 0, stream>>>(q, kb, d_out,
            (size_t)OUT_N + (size_t)l * SER_PER_L, flg);
        dim3 ag(H_, B_);
        attn_kernel<<<ag, 256, 0, stream>>>(q, kb, vb, q);
        gemm_mfma_kernel<0><<<mg, 256, 0, stream>>>(q, woh+PW, wol+PW, bo, BOFF, flg, kb, NTOK, DM_, DM_);
        ln_kernel<<<NTOK, 256, 0, stream>>>(h, kb, ln1g, ln1b, BOFF, flg);
        gemm_mfma_kernel<1><<<mg, 256, 0, stream>>>(h, c1h+PW, c1l+PW, c1b, BOFF, flg, q,  NTOK, DM_, DM_);
        gemm_mfma_kernel<0><<<mg, 256, 0, stream>>>(q, c2h+PW, c2l+PW, c2b, BOFF, flg, kb, NTOK, DM_, DM_);
        ln_kernel<<<NTOK, 256, 0, stream>>>(h, kb, ln2g, ln2b, BOFF, flg);
    }
    ln_kernel<<<NTOK, 256, 0, stream>>>(h, nullptr, lnfg, lnfb, 0, flg);

    launch_gemm(stream, 0, 0, h,  en2de_w, 0, en2de_b, 0, flg, hv, NTOK, 128, 512);
    launch_gemm(stream, 0, 0, hv, eh1w, 0, eh1b, 0, flg, h1, NTOK, 128, 128);
    launch_gemm(stream, 0, 0, h1, eh2w, 0, eh2b, 0, flg, h2, NTOK, 128, 128);
    launch_gemm(stream, 0, 0, h2, mamw, 0, mamb, 0, flg, ma,   NTOK, 64, 128);
    launch_gemm(stream, 0, 0, h2, malvw, 0, malvb, 0, flg, malv, NTOK, 64, 128);
    concat_kernel<<<(NTOK*192 + 255)/256, 256, 0, stream>>>(h1, ma, hb, NTOK*192);
    launch_gemm(stream, 0, 0, hb, zmw, 0, zmb, 0, flg, zmean, NTOK, 128, 192);
    launch_gemm(stream, 0, 0, hb, zlvw, 0, zlvb, 0, flg, zlvB,  NTOK, 128, 192);
    launch_gemm(stream, 0, 0, ma, otw, 0, otb, 0, flg, pmb, NTOK, 64, 64);
    ot_kernel<<<NTOK, 64, 0, stream>>>(pmb, theta, flg, embv, acc);
    launch_gemm(stream, 2, 0, embv, dzm1w, 0, dzm1b, 0, flg, t1, NTOK, 128, 64);
    launch_gemm(stream, 0, 0, t1, dzm2w, 0, dzm2b, 0, flg, dzmB, NTOK, 128, 128);
    launch_gemm(stream, 2, 0, embv, dzl1w, 0, dzl1b, 0, flg, t1, NTOK, 128, 64);
    launch_gemm(stream, 0, 0, t1, dzl2w, 0, dzl2b, 0, flg, dzlB, NTOK, 128, 128);
    launch_gemm(stream, 2, 0, zmean, dxm1w, 0, dxm1b, 0, flg, t1, NTOK, 128, 128);
    launch_gemm(stream, 0, 0, t1, dxm2w, 0, dxm2b, 0, flg, dxmB, NTOK, 128, 128);
    klc_kernel<<<256, 256, 0, stream>>>(ma, malv, acc);
    klz_kernel<<<256, 256, 0, stream>>>(dzmB, zmean, zlvB, dzlB, acc);
    proj_init_kernel<<<(OUT_N + 255)/256, 256, 0, stream>>>(projb, flg, outf);
    {
        dim3 pg((3800 + 63)/64, (B_ + 63)/64, PROJ_KS);
        proj_gemm_kernel<<<pg, 256, 0, stream>>>(dxmB, projw, flg, outf,
                                                 B_, 3800, 12800, 12800/PROJ_KS);
    }
    finalize_kernel<<<(OUT_N + 255)/256, 256, 0, stream>>>(outf, acc, d_out);
}

// Round 4
// 3679.232 us; speedup vs baseline: 2.0918x; 1.1991x over previous
//
#include <hip/hip_runtime.h>
#include <hip/hip_bf16.h>
#include <math.h>

typedef __hip_bfloat16 bf16;
typedef unsigned int u32;

#define B_      128
#define T_      100
#define ENC_IN_ 38
#define DM_     512
#define H_      8
#define HD_     64
#define L_      3
#define NTOK    (B_*T_)      /* 12800 */
#define K_CB    50           /* codebook size */

#define OUT_N     486400      /* B*T*C_OUT */
#define SER_N     30720000    /* L*B*H*T*T */
#define SER_PER_L 10240000    /* B*H*T*T */
#define SCALAR_BASE (OUT_N + SER_N)   /* 31206400 */

#define PROJ_KS 32            /* split-K factor for the final projection GEMM */
#define WSEG    786432        /* 3*512*512 elements per prepped weight array */

// Dual-dtype input load: inputs are either all-f32 or all-bf16.
__device__ __forceinline__ float ldin(const void* p, size_t i, int f32) {
    if (f32) return ((const float*)p)[i];
    return __bfloat162float(((const bf16*)p)[i]);
}
__device__ __forceinline__ void stout(void* p, size_t i, float v, int f32) {
    if (f32) ((float*)p)[i] = v;
    else     ((bf16*)p)[i] = __float2bfloat16(v);
}

// bf16 split helpers (RNE round to bf16; lo = residual rounded to bf16)
__device__ __forceinline__ ushort bf_hi(float x) {
    union { float f; u32 u; } c; c.f = x;
    return (ushort)((c.u + 0x7FFFu + ((c.u >> 16) & 1u)) >> 16);
}
__device__ __forceinline__ float bf_f(ushort h) {
    union { float f; u32 u; } c; c.u = (u32)h << 16; return c.f;
}

typedef __attribute__((ext_vector_type(8))) short short8v;
typedef __attribute__((ext_vector_type(4))) float f32x4;

// ---------------------------------------------------------------------------
// init: zero scalar accumulators acc[0..6]; detect input dtype from ln1g.
// ---------------------------------------------------------------------------
__global__ void init_kernel(const void* ln1g, float* acc) {
    if (threadIdx.x < 7) acc[threadIdx.x] = 0.f;
    if (threadIdx.x == 7) {
        u32 w0 = *(const u32*)ln1g;
        ((int*)acc)[7] = (w0 == 0x3F800000u) ? 1 : 0;
    }
}

// ---------------------------------------------------------------------------
// Weight prep A: transpose + bf16-split. In: W dual-dtype [3][512 k][512 n].
// Out: hi/lo bf16 bits [3][512 n][512 k].
// ---------------------------------------------------------------------------
__launch_bounds__(256)
__global__ void prep_t_kernel(const void* __restrict__ W, const int* __restrict__ flg,
                              ushort* __restrict__ hi, ushort* __restrict__ lo) {
    __shared__ float t[32][33];
    const int k0 = blockIdx.x*32, n0 = blockIdx.y*32, l = blockIdx.z;
    const int c = threadIdx.x & 31, r = threadIdx.x >> 5;   // r 0..7
    const int f32 = flg[0];
    const size_t base = (size_t)l*512*512;
#pragma unroll
    for (int i = 0; i < 4; ++i)
        t[r + i*8][c] = ldin(W, base + (size_t)(k0 + r + i*8)*512 + n0 + c, f32);
    __syncthreads();
#pragma unroll
    for (int i = 0; i < 4; ++i) {
        int a = r + i*8;                 // n within tile
        float v = t[c][a];               // = W[k0+c][n0+a]
        ushort h = bf_hi(v);
        size_t o = base + (size_t)(n0 + a)*512 + k0 + c;
        hi[o] = h;
        lo[o] = bf_hi(v - bf_f(h));
    }
}

// ---------------------------------------------------------------------------
// Weight prep B: bf16-split only (weights already [out n][in k]).
// ---------------------------------------------------------------------------
__global__ void prep_s_kernel(const void* __restrict__ W, const int* __restrict__ flg,
                              ushort* __restrict__ hi, ushort* __restrict__ lo, int n) {
    int i = blockIdx.x*256 + threadIdx.x;
    if (i >= n) return;
    float v = ldin(W, i, flg[0]);
    ushort h = bf_hi(v);
    hi[i] = h;
    lo[i] = bf_hi(v - bf_f(h));
}

// ---------------------------------------------------------------------------
// Embedding: circular conv1d(k=3) + sinusoidal positions. Block per token.
// ---------------------------------------------------------------------------
__launch_bounds__(512)
__global__ void embed_kernel(const void* __restrict__ x, const void* __restrict__ w,
                             const int* __restrict__ flg, float* __restrict__ h) {
    __shared__ float xs[3*ENC_IN_];
    const int f32 = flg[0];
    const int blk = blockIdx.x;
    const int b = blk / T_, t = blk - b*T_;
    const int tid = threadIdx.x;
    if (tid < 3*ENC_IN_) {
        int wv = tid / ENC_IN_, c = tid - wv*ENC_IN_;
        int rr = t - 1 + wv; rr = (rr + T_) % T_;
        xs[tid] = ldin(x, ((size_t)b*T_ + rr)*ENC_IN_ + c, f32);
    }
    __syncthreads();
    int i2 = tid & ~1;
    float freq = expf(-(float)i2 * (9.210340371976184f / 512.f));
    float ang = (float)t * freq;
    float s = (tid & 1) ? cosf(ang) : sinf(ang);
    for (int j = 0; j < 3*ENC_IN_; ++j)
        s = fmaf(xs[j], ldin(w, (size_t)j*DM_ + tid, f32), s);
    h[(size_t)blk*DM_ + tid] = s;
}

// ---------------------------------------------------------------------------
// MFMA GEMM (bf16x3): C = act(A @ Bprep + bias). A f32 [M][K]; B pre-split
// bf16 hi/lo [N][K]. Tile 128x128, 4 waves (2x2), per-wave 4x4 fragments of
// 16x16x32. D = Ah*Bh + Al*Bh (+ Ah*Bl when inputs f32; bf16 mode: Bl==0,
// skipped). k-permutation of fragment layout cancels (A,B loaded identically);
// C/D mapping col=lane&15, row=(lane>>4)*4+reg [m89-verified].
// LDS pitch 40 bf16 -> frag ds_read_b128 hits each bank exactly 8x (even).
// Requires M%128==0, N%128==0, K%32==0.
// ---------------------------------------------------------------------------
#define PK 40
template<int ACT>
__launch_bounds__(256, 1)
__global__ void gemm_mfma_kernel(const float* __restrict__ A,
                                 const ushort* __restrict__ Bh,
                                 const ushort* __restrict__ Bl,
                                 const void* __restrict__ bias, size_t biasoff,
                                 const int* __restrict__ flg,
                                 float* __restrict__ C, int M, int N, int K) {
    __shared__ ushort sAh[128*PK];
    __shared__ ushort sAl[128*PK];
    __shared__ ushort sBh[128*PK];
    __shared__ ushort sBl[128*PK];
    const int tid = threadIdx.x;
    const int lane = tid & 63, wid = tid >> 6;
    const int wr = wid >> 1, wc = wid & 1;
    const int m0 = blockIdx.y * 128, n0 = blockIdx.x * 128;
    const int useBl = flg[0];
    const int r  = tid >> 1;
    const int ks = (tid & 1) * 16;
    const float*  Ap  = A  + (size_t)(m0 + r)*K + ks;
    const ushort* Bhp = Bh + (size_t)(n0 + r)*K + ks;
    const ushort* Blp = Bl + (size_t)(n0 + r)*K + ks;
    const int frow = lane & 15, fk = (lane >> 4) * 8;
    const f32x4 zero = {0.f, 0.f, 0.f, 0.f};
    f32x4 acc[4][4];
#pragma unroll
    for (int m = 0; m < 4; ++m)
#pragma unroll
        for (int n = 0; n < 4; ++n) acc[m][n] = zero;

    for (int k0 = 0; k0 < K; k0 += 32) {
#pragma unroll
        for (int j = 0; j < 4; ++j) {
            float4 v = *(const float4*)(Ap + k0 + j*4);
            ushort4 hi, lo;
            hi.x = bf_hi(v.x); lo.x = bf_hi(v.x - bf_f(hi.x));
            hi.y = bf_hi(v.y); lo.y = bf_hi(v.y - bf_f(hi.y));
            hi.z = bf_hi(v.z); lo.z = bf_hi(v.z - bf_f(hi.z));
            hi.w = bf_hi(v.w); lo.w = bf_hi(v.w - bf_f(hi.w));
            *(ushort4*)&sAh[r*PK + ks + j*4] = hi;
            *(ushort4*)&sAl[r*PK + ks + j*4] = lo;
        }
        *(uint4*)&sBh[r*PK + ks]     = *(const uint4*)(Bhp + k0);
        *(uint4*)&sBh[r*PK + ks + 8] = *(const uint4*)(Bhp + k0 + 8);
        if (useBl) {
            *(uint4*)&sBl[r*PK + ks]     = *(const uint4*)(Blp + k0);
            *(uint4*)&sBl[r*PK + ks + 8] = *(const uint4*)(Blp + k0 + 8);
        }
        __syncthreads();
        short8v ah[4], al[4], bh[4];
#pragma unroll
        for (int m = 0; m < 4; ++m) {
            int row = wr*64 + m*16 + frow;
            ah[m] = *(const short8v*)&sAh[row*PK + fk];
            al[m] = *(const short8v*)&sAl[row*PK + fk];
        }
#pragma unroll
        for (int n = 0; n < 4; ++n) {
            int col = wc*64 + n*16 + frow;
            bh[n] = *(const short8v*)&sBh[col*PK + fk];
        }
#pragma unroll
        for (int m = 0; m < 4; ++m)
#pragma unroll
            for (int n = 0; n < 4; ++n) {
                acc[m][n] = __builtin_amdgcn_mfma_f32_16x16x32_bf16(ah[m], bh[n], acc[m][n], 0, 0, 0);
                acc[m][n] = __builtin_amdgcn_mfma_f32_16x16x32_bf16(al[m], bh[n], acc[m][n], 0, 0, 0);
            }
        if (useBl) {
            short8v bl[4];
#pragma unroll
            for (int n = 0; n < 4; ++n) {
                int col = wc*64 + n*16 + frow;
                bl[n] = *(const short8v*)&sBl[col*PK + fk];
            }
#pragma unroll
            for (int m = 0; m < 4; ++m)
#pragma unroll
                for (int n = 0; n < 4; ++n)
                    acc[m][n] = __builtin_amdgcn_mfma_f32_16x16x32_bf16(ah[m], bl[n], acc[m][n], 0, 0, 0);
        }
        __syncthreads();
    }
    const int f32b = flg[0];
#pragma unroll
    for (int m = 0; m < 4; ++m) {
        int row0 = m0 + wr*64 + m*16 + (lane >> 4)*4;
#pragma unroll
        for (int n = 0; n < 4; ++n) {
            int col = n0 + wc*64 + n*16 + (lane & 15);
            float bv = bias ? ldin(bias, biasoff + col, f32b) : 0.f;
#pragma unroll
            for (int i = 0; i < 4; ++i) {
                float vv = acc[m][n][i] + bv;
                if (ACT == 1) vv = 0.5f*vv*(1.f + erff(vv*0.7071067811865475f));
                C[(size_t)(row0 + i)*N + col] = vv;
            }
        }
    }
}

// ---------------------------------------------------------------------------
// Generic small GEMM: 64x64 tile, 256 threads, 4x4 microtile (decoder smalls).
// ---------------------------------------------------------------------------
template<int ACT, int TRANSB>
__launch_bounds__(256)
__global__ void gemm_kernel(const float* __restrict__ A, const void* __restrict__ Bw,
                            size_t bwoff, const void* __restrict__ bias, size_t biasoff,
                            const int* __restrict__ flg,
                            float* __restrict__ C, int M, int N, int K) {
    __shared__ float As[16][68];
    __shared__ float Bs[16][68];
    const int f32 = flg[0];
    const int tid = threadIdx.x;
    const int tx = tid & 15, ty = tid >> 4;
    const int m0 = blockIdx.y * 64, n0 = blockIdx.x * 64;
    float acc[4][4] = {};
    for (int k0 = 0; k0 < K; k0 += 16) {
        for (int i = tid; i < 1024; i += 256) {
            int r = i >> 4, kk = i & 15;
            int gm = m0 + r, gk = k0 + kk;
            As[kk][r] = (gm < M && gk < K) ? A[(size_t)gm*K + gk] : 0.f;
        }
        for (int i = tid; i < 1024; i += 256) {
            int kk, c;
            if (TRANSB) { c = i >> 4; kk = i & 15; }
            else        { kk = i >> 6; c = i & 63; }
            int gk = k0 + kk, gn = n0 + c;
            float vv = 0.f;
            if (gk < K && gn < N)
                vv = TRANSB ? ldin(Bw, bwoff + (size_t)gn*K + gk, f32)
                            : ldin(Bw, bwoff + (size_t)gk*N + gn, f32);
            Bs[kk][c] = vv;
        }
        __syncthreads();
#pragma unroll
        for (int kk = 0; kk < 16; ++kk) {
            float4 av = *(const float4*)&As[kk][ty*4];
            float4 bv = *(const float4*)&Bs[kk][tx*4];
            float a[4] = {av.x, av.y, av.z, av.w};
            float b[4] = {bv.x, bv.y, bv.z, bv.w};
#pragma unroll
            for (int ii = 0; ii < 4; ++ii)
#pragma unroll
                for (int jj = 0; jj < 4; ++jj)
                    acc[ii][jj] = fmaf(a[ii], b[jj], acc[ii][jj]);
        }
        __syncthreads();
    }
#pragma unroll
    for (int ii = 0; ii < 4; ++ii) {
        int gm = m0 + ty*4 + ii;
        if (gm >= M) continue;
#pragma unroll
        for (int jj = 0; jj < 4; ++jj) {
            int gn = n0 + tx*4 + jj;
            if (gn >= N) continue;
            float vv = acc[ii][jj] + (bias ? ldin(bias, biasoff + gn, f32) : 0.f);
            if (ACT == 1) vv = 0.5f * vv * (1.f + erff(vv * 0.7071067811865475f));
            if (ACT == 2) vv = fmaxf(vv, 0.f);
            C[(size_t)gm*N + gn] = vv;
        }
    }
}

// ---------------------------------------------------------------------------
// Split-K projection GEMM, 64x128 tile, 4x8 microtile. The 4x4 microtile is
// structurally LDS-bound (16 FMA per 32B LDS read; LDS peak 128 B/cy caps
// VALU at 50% -> measured 32%). 4x8 = 32 FMA per 48B -> ~85 B/cy LDS demand,
// VALU-issue-bound. Grid 30x2x32 = 1920 blocks keeps round-1's occupancy.
// atomicAdd into bias-prefilled C.
// ---------------------------------------------------------------------------
__launch_bounds__(256)
__global__ void proj_init_kernel(const void* __restrict__ bias,
                                 const int* __restrict__ flg,
                                 float* __restrict__ C) {
    int i = blockIdx.x*256 + threadIdx.x;
    if (i < OUT_N) C[i] = ldin(bias, (size_t)(i % 3800), flg[0]);
}

__launch_bounds__(256)
__global__ void proj_gemm_kernel(const float* __restrict__ A, const void* __restrict__ Bw,
                                 const int* __restrict__ flg, float* __restrict__ C,
                                 int M, int N, int K, int kchunk) {
    __shared__ float As[16][68];
    __shared__ float Bs[16][132];
    const int f32 = flg[0];
    const int tid = threadIdx.x;
    const int tx = tid & 15, ty = tid >> 4;
    const int m0 = blockIdx.y * 64, n0 = blockIdx.x * 128;
    const int kbeg = blockIdx.z * kchunk;
    const int kend = kbeg + kchunk;
    float acc[4][8] = {};
    for (int k0 = kbeg; k0 < kend; k0 += 16) {
        // stage A 64 rows x 16 k (transposed into As[kk][r])
        for (int i = tid; i < 1024; i += 256) {
            int r = i >> 4, kk = i & 15;
            int gm = m0 + r;
            As[kk][r] = (gm < M) ? A[(size_t)gm*K + (k0 + kk)] : 0.f;
        }
        // stage B 16 k x 128 n
        for (int i = tid; i < 2048; i += 256) {
            int kk = i >> 7, c = i & 127;
            int gn = n0 + c;
            Bs[kk][c] = (gn < N) ? ldin(Bw, (size_t)(k0 + kk)*N + gn, f32) : 0.f;
        }
        __syncthreads();
#pragma unroll
        for (int kk = 0; kk < 16; ++kk) {
            float4 av = *(const float4*)&As[kk][ty*4];
            float4 b0 = *(const float4*)&Bs[kk][tx*8];
            float4 b1 = *(const float4*)&Bs[kk][tx*8 + 4];
            float a[4] = {av.x, av.y, av.z, av.w};
            float b[8] = {b0.x,b0.y,b0.z,b0.w,b1.x,b1.y,b1.z,b1.w};
#pragma unroll
            for (int ii = 0; ii < 4; ++ii)
#pragma unroll
                for (int jj = 0; jj < 8; ++jj)
                    acc[ii][jj] = fmaf(a[ii], b[jj], acc[ii][jj]);
        }
        __syncthreads();
    }
#pragma unroll
    for (int ii = 0; ii < 4; ++ii) {
        int gm = m0 + ty*4 + ii;
        if (gm >= M) continue;
#pragma unroll
        for (int jj = 0; jj < 8; ++jj) {
            int gn = n0 + tx*8 + jj;
            if (gn >= N) continue;
            atomicAdd(&C[(size_t)gm*N + gn], acc[ii][jj]);
        }
    }
}

// ---------------------------------------------------------------------------
// Fused attention for one (b, head): computes P = softmax(0.125 Q K^T) once,
// stores P directly to the series output (dual-dtype) AND computes C = P V.
// Replaces the separate series_kernel (which recomputed the same QK^T).
// Q/Cg alias is safe: row t of Cg is written only after Q[t] is consumed,
// and future Q rows are untouched.
// ---------------------------------------------------------------------------
__launch_bounds__(256)
__global__ void attn_kernel(const float* Q, const float* __restrict__ Kg,
                            const float* __restrict__ Vg, float* Cg,
                            void* __restrict__ outb, size_t soff,
                            const int* __restrict__ flg) {
    __shared__ float Ks[T_*65];
    __shared__ float Vs[T_*65];
    __shared__ float Qrow[4][64];
    __shared__ float Prow[4][104];
    const int tid = threadIdx.x;
    const int lane = tid & 63, w = tid >> 6;
    const int hh = blockIdx.x, b = blockIdx.y;
    const int f32o = flg[0];
    const size_t base = (size_t)b*T_*DM_ + (size_t)hh*HD_;
    for (int i = tid; i < T_*HD_; i += 256) {
        int r = i >> 6, d = i & 63;
        size_t g = base + (size_t)r*DM_ + d;
        Ks[r*65+d] = Kg[g];
        Vs[r*65+d] = Vg[g];
    }
    __syncthreads();
    for (int i = 0; i < 25; ++i) {
        const int t = i*4 + w;
        Qrow[w][lane] = Q[base + (size_t)t*DM_ + lane];
        __syncthreads();
        const int s2 = 64 + lane;
        float acc1 = 0.f, acc2 = 0.f;
#pragma unroll 16
        for (int d = 0; d < 64; ++d) {
            float qd = Qrow[w][d];
            acc1 = fmaf(qd, Ks[lane*65 + d], acc1);
            if (s2 < T_) acc2 = fmaf(qd, Ks[s2*65 + d], acc2);
        }
        acc1 *= 0.125f; acc2 *= 0.125f;
        float mx = (s2 < T_) ? fmaxf(acc1, acc2) : acc1;
        for (int off = 32; off > 0; off >>= 1) mx = fmaxf(mx, __shfl_xor(mx, off));
        float e1 = expf(acc1 - mx);
        float e2 = (s2 < T_) ? expf(acc2 - mx) : 0.f;
        float sum = e1 + e2;
        for (int off = 32; off > 0; off >>= 1) sum += __shfl_xor(sum, off);
        float inv = 1.f / sum;
        float p1 = e1 * inv, p2 = e2 * inv;
        // series store (this row of P)
        size_t sb = soff + ((size_t)(b*H_ + hh)*T_ + t)*T_;
        stout(outb, sb + lane, p1, f32o);
        if (s2 < T_) stout(outb, sb + s2, p2, f32o);
        Prow[w][lane] = p1;
        if (s2 < T_) Prow[w][s2] = p2;
        __syncthreads();
        float o = 0.f;
#pragma unroll 10
        for (int s = 0; s < T_; ++s)
            o = fmaf(Prow[w][s], Vs[s*65 + lane], o);
        Cg[base + (size_t)t*DM_ + lane] = o;
    }
}

// ---------------------------------------------------------------------------
// Residual + LayerNorm over 512 dims; in-place on h.
// ---------------------------------------------------------------------------
__launch_bounds__(256)
__global__ void ln_kernel(float* __restrict__ h, const float* __restrict__ res,
                          const void* __restrict__ g, const void* __restrict__ bta,
                          size_t goff, const int* __restrict__ flg) {
    __shared__ float red[256];
    const int f32 = flg[0];
    const int row = blockIdx.x, tid = threadIdx.x;
    float* hp = h + (size_t)row*DM_;
    float x0 = hp[tid], x1 = hp[tid+256];
    if (res) {
        x0 += res[(size_t)row*DM_ + tid];
        x1 += res[(size_t)row*DM_ + tid + 256];
    }
    red[tid] = x0 + x1;
    __syncthreads();
    for (int s = 128; s > 0; s >>= 1) { if (tid < s) red[tid] += red[tid+s]; __syncthreads(); }
    float mean = red[0] * (1.f/512.f);
    __syncthreads();
    float d0 = x0 - mean, d1 = x1 - mean;
    red[tid] = d0*d0 + d1*d1;
    __syncthreads();
    for (int s = 128; s > 0; s >>= 1) { if (tid < s) red[tid] += red[tid+s]; __syncthreads(); }
    float rs = 1.f / sqrtf(red[0]*(1.f/512.f) + 1e-5f);
    hp[tid]     = d0*rs*ldin(g, goff+tid, f32)     + ldin(bta, goff+tid, f32);
    hp[tid+256] = d1*rs*ldin(g, goff+tid+256, f32) + ldin(bta, goff+tid+256, f32);
}

// ---------------------------------------------------------------------------
__global__ void concat_kernel(const float* __restrict__ h1, const float* __restrict__ ma,
                              float* __restrict__ hb, int n) {
    int i = blockIdx.x*blockDim.x + threadIdx.x;
    if (i >= n) return;
    int row = i / 192, j = i - row*192;
    hb[i] = (j < 128) ? h1[(size_t)row*128 + j] : ma[(size_t)row*64 + (j-128)];
}

// ---------------------------------------------------------------------------
// OT concept head, one block (64 threads) per token.
// ---------------------------------------------------------------------------
__launch_bounds__(64)
__global__ void ot_kernel(const float* __restrict__ pm, const void* __restrict__ theta,
                          const int* __restrict__ flg,
                          float* __restrict__ embv, float* __restrict__ acc) {
    __shared__ float th[K_CB*64];
    __shared__ float pmv[64];
    __shared__ float red[64];
    __shared__ float pvec[64];
    const int f32 = flg[0];
    const int tid = threadIdx.x;
    const int tok = blockIdx.x;
    for (int i = tid; i < K_CB*64; i += 64) th[i] = ldin(theta, i, f32);
    pmv[tid] = pm[(size_t)tok*64 + tid];
    __syncthreads();
    red[tid] = pmv[tid]*pmv[tid];
    __syncthreads();
    for (int s = 32; s > 0; s >>= 1) { if (tid < s) red[tid] += red[tid+s]; __syncthreads(); }
    float pm2 = red[0];
    __syncthreads();
    float cost = 0.f;
    if (tid < K_CB) {
        const float* tr = th + tid*64;
        float dot = 0.f, t2 = 0.f;
        for (int d = 0; d < 64; ++d) { float tv = tr[d]; dot = fmaf(pmv[d], tv, dot); t2 = fmaf(tv, tv, t2); }
        cost = pm2 - 2.f*dot + t2;
    }
    float logit = (tid < K_CB) ? (-cost / 0.1f) : -1e30f;
    red[tid] = logit;
    __syncthreads();
    for (int s = 32; s > 0; s >>= 1) { if (tid < s) red[tid] = fmaxf(red[tid], red[tid+s]); __syncthreads(); }
    float mx = red[0];
    __syncthreads();
    float e = (tid < K_CB) ? expf(logit - mx) : 0.f;
    red[tid] = e;
    __syncthreads();
    for (int s = 32; s > 0; s >>= 1) { if (tid < s) red[tid] += red[tid+s]; __syncthreads(); }
    float p = e / red[0];
    __syncthreads();
    pvec[tid] = p;
    red[tid] = p * cost;
    __syncthreads();
    for (int s = 32; s > 0; s >>= 1) { if (tid < s) red[tid] += red[tid+s]; __syncthreads(); }
    if (tid == 0) atomicAdd(acc + 0, red[0]);
    __syncthreads();
    float eb = 0.f;
    for (int kk = 0; kk < K_CB; ++kk) eb = fmaf(pvec[kk], th[kk*64 + tid], eb);
    embv[(size_t)tok*64 + tid] = eb;
    float dd = eb - pmv[tid];
    red[tid] = dd*dd;
    __syncthreads();
    for (int s = 32; s > 0; s >>= 1) { if (tid < s) red[tid] += red[tid+s]; __syncthreads(); }
    if (tid == 0) atomicAdd(acc + 1, red[0]);
}

// ---------------------------------------------------------------------------
__global__ void klc_kernel(const float* __restrict__ m, const float* __restrict__ lv,
                           float* __restrict__ acc) {
    __shared__ float red[256];
    const int tid = threadIdx.x;
    float s = 0.f;
    for (int i = blockIdx.x*256 + tid; i < NTOK*64; i += gridDim.x*256) {
        float mm = m[i], l = lv[i];
        s += -0.5f * (1.f - mm*mm + l - expf(l));
    }
    red[tid] = s; __syncthreads();
    for (int st = 128; st > 0; st >>= 1) { if (tid < st) red[tid] += red[tid+st]; __syncthreads(); }
    if (tid == 0) atomicAdd(acc + 2, red[0]);
}

__global__ void klz_kernel(const float* __restrict__ dzm, const float* __restrict__ zm,
                           const float* __restrict__ zlv, const float* __restrict__ dzl,
                           float* __restrict__ acc) {
    __shared__ float red[256];
    const int tid = threadIdx.x;
    float s = 0.f;
    for (int i = blockIdx.x*256 + tid; i < NTOK*128; i += gridDim.x*256) {
        float d = dzm[i] - zm[i];
        float zl = zlv[i], dl = dzl[i];
        s += 0.5f * (d*d / expf(zl) + expf(dl - zl) - 1.f - (dl - zl));
    }
    red[tid] = s; __syncthreads();
    for (int st = 128; st > 0; st >>= 1) { if (tid < st) red[tid] += red[tid+st]; __syncthreads(); }
    if (tid == 0) atomicAdd(acc + 3, red[0]);
}

// ---------------------------------------------------------------------------
__global__ void finalize_kernel(const float* __restrict__ outf, const float* __restrict__ acc,
                                void* __restrict__ outb) {
    const int f32 = ((const int*)acc)[7];
    int i = blockIdx.x*blockDim.x + threadIdx.x;
    if (i < OUT_N) stout(outb, i, outf[i], f32);
    if (i == 0) {
        stout(outb, SCALAR_BASE + 0, acc[0] * (1.f/12800.f),   f32);
        stout(outb, SCALAR_BASE + 1, acc[1] * (1.f/819200.f),  f32);
        stout(outb, SCALAR_BASE + 2, acc[2] * (1.f/819200.f),  f32);
        stout(outb, SCALAR_BASE + 3, acc[3] * (1.f/1638400.f), f32);
    }
}

// ---------------------------------------------------------------------------
static inline void launch_gemm(hipStream_t st, int act, int transb,
                               const float* A, const void* Bw, size_t bwoff,
                               const void* bias, size_t biasoff,
                               const int* flg, float* C, int M, int N, int K) {
    dim3 g((N + 63)/64, (M + 63)/64);
    if      (act == 0 && !transb) gemm_kernel<0,0><<<g,256,0,st>>>(A,Bw,bwoff,bias,biasoff,flg,C,M,N,K);
    else if (act == 0 &&  transb) gemm_kernel<0,1><<<g,256,0,st>>>(A,Bw,bwoff,bias,biasoff,flg,C,M,N,K);
    else if (act == 1)            gemm_kernel<1,1><<<g,256,0,st>>>(A,Bw,bwoff,bias,biasoff,flg,C,M,N,K);
    else                          gemm_kernel<2,0><<<g,256,0,st>>>(A,Bw,bwoff,bias,biasoff,flg,C,M,N,K);
}

extern "C" void kernel_launch(void* const* d_in, const int* in_sizes, int n_in,
                              void* d_out, int out_size, void* d_ws, size_t ws_size,
                              hipStream_t stream) {
    const void* x      = d_in[0];
    const void* emb_w  = d_in[1];
    const void* Wq     = d_in[2];
    const void* Wk     = d_in[3];
    const void* Wv     = d_in[4];
    const void* Wo     = d_in[5];
    const void* bq     = d_in[6];
    const void* bk     = d_in[7];
    const void* bv     = d_in[8];
    const void* bo     = d_in[9];
    const void* c1w    = d_in[10];
    const void* c1b    = d_in[11];
    const void* c2w    = d_in[12];
    const void* c2b    = d_in[13];
    const void* ln1g   = d_in[14];
    const void* ln1b   = d_in[15];
    const void* ln2g   = d_in[16];
    const void* ln2b   = d_in[17];
    const void* lnfg   = d_in[18];
    const void* lnfb   = d_in[19];
    const void* en2de_w= d_in[20];
    const void* en2de_b= d_in[21];
    const void* eh1w   = d_in[22];
    const void* eh1b   = d_in[23];
    const void* eh2w   = d_in[24];
    const void* eh2b   = d_in[25];
    const void* mamw   = d_in[26];
    const void* mamb   = d_in[27];
    const void* malvw  = d_in[28];
    const void* malvb  = d_in[29];
    const void* zmw    = d_in[30];
    const void* zmb    = d_in[31];
    const void* zlvw   = d_in[32];
    const void* zlvb   = d_in[33];
    const void* dzm1w  = d_in[34];
    const void* dzm1b  = d_in[35];
    const void* dzm2w  = d_in[36];
    const void* dzm2b  = d_in[37];
    const void* dzl1w  = d_in[38];
    const void* dzl1b  = d_in[39];
    const void* dzl2w  = d_in[40];
    const void* dzl2b  = d_in[41];
    const void* dxm1w  = d_in[42];
    const void* dxm1b  = d_in[43];
    const void* dxm2w  = d_in[44];
    const void* dxm2b  = d_in[45];
    const void* otw    = d_in[46];
    const void* otb    = d_in[47];
    const void* theta  = d_in[48];
    const void* projw  = d_in[49];
    const void* projb  = d_in[50];

    float* ws = (float*)d_ws;
    const size_t NBUF = (size_t)NTOK * DM_;
    float* acc = ws;                                 // acc[0..6] + flag at [7]
    const int* flg = (const int*)ws + 7;
    float* h  = ws + 16;
    float* q  = h + NBUF;
    float* kb = h + 2*NBUF;
    float* vb = h + 3*NBUF;
    float* hv    = q;
    float* h1    = q  + 1638400;
    float* h2    = q  + 3276800;
    float* ma    = q  + 4915200;
    float* malv  = q  + 5734400;
    float* hb    = kb;
    float* zmean = kb + 2457600;
    float* zlvB  = kb + 4096000;
    float* pmb   = kb + 5734400;
    float* embv  = vb;
    float* t1    = vb + 819200;
    float* dzmB  = vb + 2457600;
    float* dzlB  = vb + 4096000;
    float* dxmB  = h;
    float* outf  = h + 1638400;
    // pre-split bf16 weight region beyond the 4 NBUF f32 buffers (18.9 MB)
    ushort* wp  = (ushort*)(vb + NBUF);
    ushort* wqh = wp;            ushort* wql = wp + 1*(size_t)WSEG;
    ushort* wkh = wp + 2*(size_t)WSEG;   ushort* wkl = wp + 3*(size_t)WSEG;
    ushort* wvh = wp + 4*(size_t)WSEG;   ushort* wvl = wp + 5*(size_t)WSEG;
    ushort* woh = wp + 6*(size_t)WSEG;   ushort* wol = wp + 7*(size_t)WSEG;
    ushort* c1h = wp + 8*(size_t)WSEG;   ushort* c1l = wp + 9*(size_t)WSEG;
    ushort* c2h = wp + 10*(size_t)WSEG;  ushort* c2l = wp + 11*(size_t)WSEG;

    init_kernel<<<1, 64, 0, stream>>>(ln1g, acc);
    {
        dim3 tg(16, 16, 3);
        prep_t_kernel<<<tg, 256, 0, stream>>>(Wq, flg, wqh, wql);
        prep_t_kernel<<<tg, 256, 0, stream>>>(Wk, flg, wkh, wkl);
        prep_t_kernel<<<tg, 256, 0, stream>>>(Wv, flg, wvh, wvl);
        prep_t_kernel<<<tg, 256, 0, stream>>>(Wo, flg, woh, wol);
        prep_s_kernel<<<(WSEG + 255)/256, 256, 0, stream>>>(c1w, flg, c1h, c1l, WSEG);
        prep_s_kernel<<<(WSEG + 255)/256, 256, 0, stream>>>(c2w, flg, c2h, c2l, WSEG);
    }
    embed_kernel<<<NTOK, 512, 0, stream>>>(x, emb_w, flg, h);

    const dim3 mg(4, 100);   // N=512 -> 4 tiles, M=12800 -> 100 tiles
    for (int l = 0; l < L_; ++l) {
        const size_t PW = (size_t)l * DM_ * DM_;
        const size_t BOFF = (size_t)l * DM_;
        gemm_mfma_kernel<0><<<mg, 256, 0, stream>>>(h, wqh+PW, wql+PW, bq, BOFF, flg, q,  NTOK, DM_, DM_);
        gemm_mfma_kernel<0><<<mg, 256, 0, stream>>>(h, wkh+PW, wkl+PW, bk, BOFF, flg, kb, NTOK, DM_, DM_);
        gemm_mfma_kernel<0><<<mg, 256, 0, stream>>>(h, wvh+PW, wvl+PW, bv, BOFF, flg, vb, NTOK, DM_, DM_);
        // fused attention: writes series P rows to d_out AND context into q
        dim3 ag(H_, B_);
        attn_kernel<<<ag, 256, 0, stream>>>(q, kb, vb, q, d_out,
            (size_t)OUT_N + (size_t)l * SER_PER_L, flg);
        gemm_mfma_kernel<0><<<mg, 256, 0, stream>>>(q, woh+PW, wol+PW, bo, BOFF, flg, kb, NTOK, DM_, DM_);
        ln_kernel<<<NTOK, 256, 0, stream>>>(h, kb, ln1g, ln1b, BOFF, flg);
        gemm_mfma_kernel<1><<<mg, 256, 0, stream>>>(h, c1h+PW, c1l+PW, c1b, BOFF, flg, q,  NTOK, DM_, DM_);
        gemm_mfma_kernel<0><<<mg, 256, 0, stream>>>(q, c2h+PW, c2l+PW, c2b, BOFF, flg, kb, NTOK, DM_, DM_);
        ln_kernel<<<NTOK, 256, 0, stream>>>(h, kb, ln2g, ln2b, BOFF, flg);
    }
    ln_kernel<<<NTOK, 256, 0, stream>>>(h, nullptr, lnfg, lnfb, 0, flg);

    launch_gemm(stream, 0, 0, h,  en2de_w, 0, en2de_b, 0, flg, hv, NTOK, 128, 512);
    launch_gemm(stream, 0, 0, hv, eh1w, 0, eh1b, 0, flg, h1, NTOK, 128, 128);
    launch_gemm(stream, 0, 0, h1, eh2w, 0, eh2b, 0, flg, h2, NTOK, 128, 128);
    launch_gemm(stream, 0, 0, h2, mamw, 0, mamb, 0, flg, ma,   NTOK, 64, 128);
    launch_gemm(stream, 0, 0, h2, malvw, 0, malvb, 0, flg, malv, NTOK, 64, 128);
    concat_kernel<<<(NTOK*192 + 255)/256, 256, 0, stream>>>(h1, ma, hb, NTOK*192);
    launch_gemm(stream, 0, 0, hb, zmw, 0, zmb, 0, flg, zmean, NTOK, 128, 192);
    launch_gemm(stream, 0, 0, hb, zlvw, 0, zlvb, 0, flg, zlvB,  NTOK, 128, 192);
    launch_gemm(stream, 0, 0, ma, otw, 0, otb, 0, flg, pmb, NTOK, 64, 64);
    ot_kernel<<<NTOK, 64, 0, stream>>>(pmb, theta, flg, embv, acc);
    launch_gemm(stream, 2, 0, embv, dzm1w, 0, dzm1b, 0, flg, t1, NTOK, 128, 64);
    launch_gemm(stream, 0, 0, t1, dzm2w, 0, dzm2b, 0, flg, dzmB, NTOK, 128, 128);
    launch_gemm(stream, 2, 0, embv, dzl1w, 0, dzl1b, 0, flg, t1, NTOK, 128, 64);
    launch_gemm(stream, 0, 0, t1, dzl2w, 0, dzl2b, 0, flg, dzlB, NTOK, 128, 128);
    launch_gemm(stream, 2, 0, zmean, dxm1w, 0, dxm1b, 0, flg, t1, NTOK, 128, 128);
    launch_gemm(stream, 0, 0, t1, dxm2w, 0, dxm2b, 0, flg, dxmB, NTOK, 128, 128);
    klc_kernel<<<256, 256, 0, stream>>>(ma, malv, acc);
    klz_kernel<<<256, 256, 0, stream>>>(dzmB, zmean, zlvB, dzlB, acc);
    // Final projection: split-K 4x8 microtile, grid 30x2x32 = 1920 blocks.
    proj_init_kernel<<<(OUT_N + 255)/256, 256, 0, stream>>>(projb, flg, outf);
    {
        dim3 pg((3800 + 127)/128, (B_ + 63)/64, PROJ_KS);
        proj_gemm_kernel<<<pg, 256, 0, stream>>>(dxmB, projw, flg, outf,
                                                 B_, 3800, 12800, 12800/PROJ_KS);
    }
    finalize_kernel<<<(OUT_N + 255)/256, 256, 0, stream>>>(outf, acc, d_out);
}